// Round 1
// baseline (2013.494 us; speedup 1.0000x reference)
//
#include <hip/hip_runtime.h>
#include <hip/hip_bf16.h>
#include <cfloat>
#include <math.h>

// Problem constants
#define T_SEQ 2048
#define HID 2048
#define NH 16
#define NKV 8
#define DH 128
#define HALF 64

// ---------------- SGEMM: C = A(MxK) @ B(KxN), all row-major fp32 ----------
#define TS 128
#define BK 16
__global__ __launch_bounds__(256) void sgemm_kernel(
    const float* __restrict__ A, const float* __restrict__ B,
    float* __restrict__ C, int M, int N, int K) {
  __shared__ float As[BK][TS + 4];   // transposed A tile, pad 4 -> stores 2-way (free), reads clean
  __shared__ float Bs[BK][TS + 4];
  const int tid = threadIdx.x;
  const int tx = tid & 15, ty = tid >> 4;
  const int m0 = blockIdx.y * TS, n0 = blockIdx.x * TS;
  float acc[8][8];
#pragma unroll
  for (int i = 0; i < 8; ++i)
#pragma unroll
    for (int j = 0; j < 8; ++j) acc[i][j] = 0.f;

  for (int k0 = 0; k0 < K; k0 += BK) {
#pragma unroll
    for (int p = 0; p < 2; ++p) {
      int row = (tid >> 2) + p * 64;
      int kq = (tid & 3) * 4;
      float4 av = *(const float4*)(A + (size_t)(m0 + row) * K + k0 + kq);
      As[kq + 0][row] = av.x; As[kq + 1][row] = av.y;
      As[kq + 2][row] = av.z; As[kq + 3][row] = av.w;
    }
#pragma unroll
    for (int p = 0; p < 2; ++p) {
      int row = (tid >> 5) + p * 8;
      int c = (tid & 31) * 4;
      *(float4*)(&Bs[row][c]) = *(const float4*)(B + (size_t)(k0 + row) * N + n0 + c);
    }
    __syncthreads();
#pragma unroll
    for (int k = 0; k < BK; ++k) {
      float a[8], b[8];
      *(float4*)(a)     = *(const float4*)(&As[k][ty * 8]);
      *(float4*)(a + 4) = *(const float4*)(&As[k][ty * 8 + 4]);
      *(float4*)(b)     = *(const float4*)(&Bs[k][tx * 8]);
      *(float4*)(b + 4) = *(const float4*)(&Bs[k][tx * 8 + 4]);
#pragma unroll
      for (int i = 0; i < 8; ++i)
#pragma unroll
        for (int j = 0; j < 8; ++j) acc[i][j] += a[i] * b[j];
    }
    __syncthreads();
  }
#pragma unroll
  for (int i = 0; i < 8; ++i) {
    int m = m0 + ty * 8 + i;
    float4 v0 = {acc[i][0], acc[i][1], acc[i][2], acc[i][3]};
    float4 v1 = {acc[i][4], acc[i][5], acc[i][6], acc[i][7]};
    float* cp = C + (size_t)m * N + n0 + tx * 8;
    *(float4*)(cp)     = v0;
    *(float4*)(cp + 4) = v1;
  }
}

// ------------- RMSNorm + RoPE, in place on q (inside qg) and k ------------
// grid: (T_SEQ, NH + NKV), block: 128 (one thread per dim)
__global__ __launch_bounds__(128) void norm_rope_kernel(
    float* __restrict__ qg, float* __restrict__ kb,
    const int* __restrict__ positions,
    const float* __restrict__ qw, const float* __restrict__ kw) {
  const int t = blockIdx.x, hh = blockIdx.y, d = threadIdx.x;
  float* x; const float* w;
  if (hh < NH) { x = qg + ((size_t)t * NH + hh) * (2 * DH); w = qw; }
  else         { x = kb + ((size_t)t * NKV + (hh - NH)) * DH; w = kw; }
  float v = x[d];
  float ss = v * v;
#pragma unroll
  for (int off = 32; off >= 1; off >>= 1) ss += __shfl_xor(ss, off, 64);
  __shared__ float red[2];
  if ((d & 63) == 0) red[d >> 6] = ss;
  __syncthreads();
  float mean = (red[0] + red[1]) * (1.0f / 128.0f);
  float xn = v * rsqrtf(mean + 1e-6f) * (1.0f + w[d]);
  __shared__ float sh[128];
  sh[d] = xn;
  __syncthreads();
  if (d < HALF) {
    float pos = (float)positions[t];
    // inv_freq = 10000^(-d/64) = 2^(-d/64 * log2(10000))
    float freq = pos * exp2f(-(float)d * (13.287712379549449f / 64.0f));
    float s, c;
    sincosf(freq, &s, &c);  // accurate libm version (RoPE runs once; cheap)
    float x1 = sh[d], x2 = sh[d + HALF];
    x[d]        = x1 * c - x2 * s;
    x[d + HALF] = x2 * c + x1 * s;
  }
}

// ---------------- Flash-style causal GQA attention + sigmoid gate ---------
// grid: (T_SEQ/64, NH), block 256. Each block: 64 q-rows of one head.
// thread (r = tid>>2, qd = tid&3): scores for keys s = qd+4j; owns d-chunks
// c = qd + 4*i4 (float4 chunks, interleaved so Vs reads are conflict-free).
#define AQT 64
#define AKT 32
__global__ __launch_bounds__(256) void attn_kernel(
    const float* __restrict__ qg, const float* __restrict__ kb,
    const float* __restrict__ vb, float* __restrict__ obuf) {
  const int qtile = blockIdx.x, h = blockIdx.y;
  const int tid = threadIdx.x;
  const int r = tid >> 2, qd = tid & 3;
  const int q0 = qtile * AQT;
  const int kvh = h >> 1;          // H/KV = 2
  __shared__ float Qs[AQT][DH + 4];
  __shared__ float Ks[AKT][DH + 4];
  __shared__ float Vs[AKT][DH + 4];
  __shared__ float Ps[AQT][AKT + 1];

  // load Q tile (64 x 128)
#pragma unroll
  for (int p = 0; p < 8; ++p) {
    int idx = p * 256 + tid;
    int row = idx >> 5;
    int c = (idx & 31) * 4;
    *(float4*)(&Qs[row][c]) =
        *(const float4*)(qg + ((size_t)(q0 + row) * NH + h) * (2 * DH) + c);
  }

  float m = -INFINITY, l = 0.f;
  float o[32];
#pragma unroll
  for (int i = 0; i < 32; ++i) o[i] = 0.f;

  const float scaling = 0.08838834764831845f;  // 128^-0.5
  const int nkt = (q0 + AQT) / AKT;
  const int tq = q0 + r;

  for (int kt = 0; kt < nkt; ++kt) {
    __syncthreads();  // prior iter's Ps/Vs reads done before overwrite
#pragma unroll
    for (int p = 0; p < 4; ++p) {
      int idx = p * 256 + tid;
      int row = idx >> 5;
      int c = (idx & 31) * 4;
      size_t g = ((size_t)(kt * AKT + row) * NKV + kvh) * DH + c;
      *(float4*)(&Ks[row][c]) = *(const float4*)(kb + g);
      *(float4*)(&Vs[row][c]) = *(const float4*)(vb + g);
    }
    __syncthreads();

    // scores: 8 keys per thread (s = qd + 4j)
    float sc[8];
#pragma unroll
    for (int j = 0; j < 8; ++j) sc[j] = 0.f;
    for (int d4 = 0; d4 < 32; ++d4) {
      float4 qv = *(const float4*)(&Qs[r][d4 * 4]);
#pragma unroll
      for (int j = 0; j < 8; ++j) {
        float4 kv = *(const float4*)(&Ks[qd + 4 * j][d4 * 4]);
        sc[j] += qv.x * kv.x + qv.y * kv.y + qv.z * kv.z + qv.w * kv.w;
      }
    }
    float tmax = -FLT_MAX;
#pragma unroll
    for (int j = 0; j < 8; ++j) {
      int s = kt * AKT + qd + 4 * j;
      sc[j] = (s <= tq) ? sc[j] * scaling : -FLT_MAX;
      tmax = fmaxf(tmax, sc[j]);
    }
    tmax = fmaxf(tmax, __shfl_xor(tmax, 1, 64));
    tmax = fmaxf(tmax, __shfl_xor(tmax, 2, 64));
    float mnew = fmaxf(m, tmax);
    float alpha = __expf(m - mnew);  // m=-inf first iter -> alpha=0 (safe)
    float p8[8], psum = 0.f;
#pragma unroll
    for (int j = 0; j < 8; ++j) { p8[j] = __expf(sc[j] - mnew); psum += p8[j]; }
    psum += __shfl_xor(psum, 1, 64);
    psum += __shfl_xor(psum, 2, 64);
    l = l * alpha + psum;
    m = mnew;
#pragma unroll
    for (int i = 0; i < 32; ++i) o[i] *= alpha;
#pragma unroll
    for (int j = 0; j < 8; ++j) Ps[r][qd + 4 * j] = p8[j];
    __syncthreads();

    // PV: o[c-chunks] += p * V
    for (int s = 0; s < AKT; ++s) {
      float pv = Ps[r][s];
#pragma unroll
      for (int i4 = 0; i4 < 8; ++i4) {
        int c = (qd + 4 * i4) * 4;
        float4 vv = *(const float4*)(&Vs[s][c]);
        o[i4 * 4 + 0] += pv * vv.x;
        o[i4 * 4 + 1] += pv * vv.y;
        o[i4 * 4 + 2] += pv * vv.z;
        o[i4 * 4 + 3] += pv * vv.w;
      }
    }
  }

  // epilogue: o = (o/l) * sigmoid(gate); write to obuf (T, H*D)
  float inv_l = 1.0f / l;
  const float* gptr = qg + ((size_t)tq * NH + h) * (2 * DH) + DH;
  float* optr = obuf + (size_t)tq * (NH * DH) + h * DH;
#pragma unroll
  for (int i4 = 0; i4 < 8; ++i4) {
    int c = (qd + 4 * i4) * 4;
    float4 g4 = *(const float4*)(gptr + c);
    float4 ov;
    ov.x = o[i4 * 4 + 0] * inv_l / (1.f + __expf(-g4.x));
    ov.y = o[i4 * 4 + 1] * inv_l / (1.f + __expf(-g4.y));
    ov.z = o[i4 * 4 + 2] * inv_l / (1.f + __expf(-g4.z));
    ov.w = o[i4 * 4 + 3] * inv_l / (1.f + __expf(-g4.w));
    *(float4*)(optr + c) = ov;
  }
}

extern "C" void kernel_launch(void* const* d_in, const int* in_sizes, int n_in,
                              void* d_out, int out_size, void* d_ws, size_t ws_size,
                              hipStream_t stream) {
  const int*   positions = (const int*)d_in[0];
  const float* hs        = (const float*)d_in[1];
  const float* Wq        = (const float*)d_in[2];
  const float* Wk        = (const float*)d_in[3];
  const float* Wv        = (const float*)d_in[4];
  const float* Wo        = (const float*)d_in[5];
  const float* qnw       = (const float*)d_in[6];
  const float* knw       = (const float*)d_in[7];
  float* out = (float*)d_out;

  // workspace layout (floats)
  float* qg = (float*)d_ws;                       // T x H x 2D   = 8388608
  float* kb = qg + (size_t)T_SEQ * NH * 2 * DH;   // T x KV x D   = 2097152
  float* vb = kb + (size_t)T_SEQ * NKV * DH;      // T x KV x D   = 2097152
  float* ob = vb + (size_t)T_SEQ * NKV * DH;      // T x H*D      = 4194304

  // 1) projections
  sgemm_kernel<<<dim3((NH * 2 * DH) / TS, T_SEQ / TS), 256, 0, stream>>>(
      hs, Wq, qg, T_SEQ, NH * 2 * DH, HID);
  sgemm_kernel<<<dim3((NKV * DH) / TS, T_SEQ / TS), 256, 0, stream>>>(
      hs, Wk, kb, T_SEQ, NKV * DH, HID);
  sgemm_kernel<<<dim3((NKV * DH) / TS, T_SEQ / TS), 256, 0, stream>>>(
      hs, Wv, vb, T_SEQ, NKV * DH, HID);

  // 2) RMSNorm + RoPE in place on q (within qg) and k
  norm_rope_kernel<<<dim3(T_SEQ, NH + NKV), 128, 0, stream>>>(
      qg, kb, positions, qnw, knw);

  // 3) causal GQA attention + sigmoid gate
  attn_kernel<<<dim3(T_SEQ / AQT, NH), 256, 0, stream>>>(qg, kb, vb, ob);

  // 4) output projection
  sgemm_kernel<<<dim3(HID / TS, T_SEQ / TS), 256, 0, stream>>>(
      ob, Wo, out, T_SEQ, HID, HID);
}

// Round 2
// 451.921 us; speedup vs baseline: 4.4554x; 4.4554x over previous
//
#include <hip/hip_runtime.h>
#include <stdint.h>
#include <math.h>

// Problem constants
#define T_SEQ 2048
#define HID   2048
#define NH    16
#define NKV   8
#define DH    128

typedef __bf16 bf16x8 __attribute__((ext_vector_type(8)));
typedef float  f32x4  __attribute__((ext_vector_type(4)));

__device__ __forceinline__ ushort f2bf(float f) {   // round-to-nearest-even
  uint32_t u = __float_as_uint(f);
  u += 0x7FFF + ((u >> 16) & 1);
  return (ushort)(u >> 16);
}
__device__ __forceinline__ float bf2f(ushort u) {
  return __uint_as_float(((uint32_t)u) << 16);
}
// async global->LDS, 16B per lane; LDS dest = wave-uniform base + lane*16
__device__ __forceinline__ void gld16(const void* g, void* l) {
  __builtin_amdgcn_global_load_lds(
      (const __attribute__((address_space(1))) uint32_t*)g,
      (__attribute__((address_space(3))) uint32_t*)l, 16, 0, 0);
}

// ---------------- fp32 -> bf16 flat convert ----------------
__global__ __launch_bounds__(256) void conv_bf16(const float* __restrict__ s,
                                                 ushort* __restrict__ d) {
  int i = (blockIdx.x * 256 + threadIdx.x) * 4;
  float4 v = *(const float4*)(s + i);
  ushort4 o = {f2bf(v.x), f2bf(v.y), f2bf(v.z), f2bf(v.w)};
  *(ushort4*)(d + i) = o;
}

// ---------------- transpose (+convert) to bf16: dst[n][k] = src[k][n] -----
template <typename TIN>
__global__ __launch_bounds__(256) void transpose_to_bf16(
    const TIN* __restrict__ src, ushort* __restrict__ dst, int R, int Ncols) {
  __shared__ float tile[32][33];
  const int bi = blockIdx.y, bj = blockIdx.x;
  const int row = threadIdx.x >> 3, c4 = (threadIdx.x & 7) * 4;
  const TIN* sp = src + (size_t)(bi * 32 + row) * Ncols + bj * 32 + c4;
  if constexpr (sizeof(TIN) == 4) {
    float4 v = *(const float4*)sp;
    tile[row][c4 + 0] = v.x; tile[row][c4 + 1] = v.y;
    tile[row][c4 + 2] = v.z; tile[row][c4 + 3] = v.w;
  } else {
    ushort4 v = *(const ushort4*)sp;
    tile[row][c4 + 0] = bf2f(v.x); tile[row][c4 + 1] = bf2f(v.y);
    tile[row][c4 + 2] = bf2f(v.z); tile[row][c4 + 3] = bf2f(v.w);
  }
  __syncthreads();
  ushort4 o = {f2bf(tile[c4 + 0][row]), f2bf(tile[c4 + 1][row]),
               f2bf(tile[c4 + 2][row]), f2bf(tile[c4 + 3][row])};
  *(ushort4*)(dst + (size_t)(bj * 32 + row) * R + bi * 32 + c4) = o;
}

// ---------------- bf16 MFMA GEMM: C[M,N] = A[M,K] @ Bt[N,K]^T -------------
// 128x128 tile, BK=32, 4 waves each 64x64 (4x4 of 16x16x32 MFMA).
// LDS chunk-swizzled (phys_chunk = logical ^ ((row>>1)&3)) -> frag reads are
// 2-way (free); staging swizzles the GLOBAL chunk so global_load_lds's
// lane-ordered LDS write stays legal (no padding allowed).
template <int OUT_BF16>
__global__ __launch_bounds__(256) void gemm_bt(
    const ushort* __restrict__ A, const ushort* __restrict__ Bt,
    float* __restrict__ Cf, ushort* __restrict__ Cb, int M, int N, int K) {
  __shared__ ushort As[128 * 32];
  __shared__ ushort Bs[128 * 32];
  const int tid = threadIdx.x, lane = tid & 63, w = tid >> 6;
  const int quad = lane >> 4, l15 = lane & 15;
  const int wm = (w >> 1) * 64, wn = (w & 1) * 64;
  const int m0 = blockIdx.y * 128, n0 = blockIdx.x * 128;
  f32x4 acc[4][4];
#pragma unroll
  for (int i = 0; i < 4; ++i)
#pragma unroll
    for (int j = 0; j < 4; ++j) acc[i][j] = (f32x4){0.f, 0.f, 0.f, 0.f};

  const int srow = tid >> 2, sch = tid & 3;
  for (int k0 = 0; k0 < K; k0 += 32) {
    __syncthreads();
#pragma unroll
    for (int p = 0; p < 2; ++p) {
      int row = p * 64 + srow;
      int gch = sch ^ ((row >> 1) & 3);
      gld16(A + (size_t)(m0 + row) * K + k0 + gch * 8,
            As + (p * 256 + w * 64) * 8);
      gld16(Bt + (size_t)(n0 + row) * K + k0 + gch * 8,
            Bs + (p * 256 + w * 64) * 8);
    }
    __syncthreads();
    bf16x8 af[4], bfr[4];
#pragma unroll
    for (int mi = 0; mi < 4; ++mi) {
      int row = wm + mi * 16 + l15;
      int pch = quad ^ ((row >> 1) & 3);
      af[mi] = *(const bf16x8*)(As + row * 32 + pch * 8);
    }
#pragma unroll
    for (int ni = 0; ni < 4; ++ni) {
      int row = wn + ni * 16 + l15;
      int pch = quad ^ ((row >> 1) & 3);
      bfr[ni] = *(const bf16x8*)(Bs + row * 32 + pch * 8);
    }
#pragma unroll
    for (int mi = 0; mi < 4; ++mi)
#pragma unroll
      for (int ni = 0; ni < 4; ++ni)
        acc[mi][ni] = __builtin_amdgcn_mfma_f32_16x16x32_bf16(
            af[mi], bfr[ni], acc[mi][ni], 0, 0, 0);
  }
  // C/D layout: col = lane&15, row = quad*4 + reg
#pragma unroll
  for (int mi = 0; mi < 4; ++mi)
#pragma unroll
    for (int ni = 0; ni < 4; ++ni)
#pragma unroll
      for (int r = 0; r < 4; ++r) {
        int row = m0 + wm + mi * 16 + quad * 4 + r;
        int col = n0 + wn + ni * 16 + l15;
        if (OUT_BF16) Cb[(size_t)row * N + col] = f2bf(acc[mi][ni][r]);
        else          Cf[(size_t)row * N + col] = acc[mi][ni][r];
      }
}

// ---------------- RMSNorm + RoPE (bf16 in -> bf16 out) --------------------
__global__ __launch_bounds__(128) void norm_rope(
    const ushort* __restrict__ qg16, const ushort* __restrict__ kb16,
    const int* __restrict__ positions, const float* __restrict__ qw,
    const float* __restrict__ kw, ushort* __restrict__ q16,
    ushort* __restrict__ k16) {
  const int t = blockIdx.x, hh = blockIdx.y, d = threadIdx.x;
  const ushort* x; const float* wgt; ushort* out;
  if (hh < NH) {
    x = qg16 + ((size_t)t * NH + hh) * (2 * DH); wgt = qw;
    out = q16 + ((size_t)t * NH + hh) * DH;
  } else {
    x = kb16 + ((size_t)t * NKV + (hh - NH)) * DH; wgt = kw;
    out = k16 + ((size_t)t * NKV + (hh - NH)) * DH;
  }
  float v = bf2f(x[d]);
  float ss = v * v;
#pragma unroll
  for (int off = 32; off >= 1; off >>= 1) ss += __shfl_xor(ss, off, 64);
  __shared__ float red[2];
  if ((d & 63) == 0) red[d >> 6] = ss;
  __syncthreads();
  float mean = (red[0] + red[1]) * (1.0f / 128.0f);
  float xn = v * rsqrtf(mean + 1e-6f) * (1.0f + wgt[d]);
  __shared__ float sh[128];
  sh[d] = xn;
  __syncthreads();
  if (d < 64) {
    float pos = (float)positions[t];
    float freq = pos * exp2f(-(float)d * (13.287712379549449f / 64.0f));
    float s, c;
    sincosf(freq, &s, &c);
    float x1 = sh[d], x2 = sh[d + 64];
    out[d]      = f2bf(x1 * c - x2 * s);
    out[d + 64] = f2bf(x2 * c + x1 * s);
  }
}

// ---------------- MFMA flash attention + sigmoid gate ---------------------
// block = 4 waves; wave w owns q-rows [q0+w*16, +16). K-tile = 64 keys.
// Q frags register-resident. Ks[key][d] (16 chunks/row, swizzle ^(row&15));
// Vs[d][key] (8 chunks/row, swizzle ^(row&7)) staged from pre-transposed
// v16t. P does LDS round-trip (C-layout -> A-layout), padded rows (+8).
__global__ __launch_bounds__(256) void attn_mfma(
    const ushort* __restrict__ q16, const ushort* __restrict__ k16,
    const ushort* __restrict__ v16t, const ushort* __restrict__ qg16,
    ushort* __restrict__ ob16) {
  const int qt = blockIdx.x, h = blockIdx.y, kvh = h >> 1;
  const int tid = threadIdx.x, lane = tid & 63, w = tid >> 6;
  const int quad = lane >> 4, l15 = lane & 15;
  const int q0 = qt * 64;

  __shared__ ushort Ks[64 * 128];
  __shared__ ushort Vs[128 * 64];
  __shared__ ushort Ps[4][16][72];   // per-wave, row stride 144B (16B-aligned)

  bf16x8 qf[4];
  const ushort* qbase = q16 + ((size_t)(q0 + w * 16 + l15) * NH + h) * DH;
#pragma unroll
  for (int ks = 0; ks < 4; ++ks)
    qf[ks] = *(const bf16x8*)(qbase + ks * 32 + quad * 8);

  f32x4 oacc[8];
#pragma unroll
  for (int i = 0; i < 8; ++i) oacc[i] = (f32x4){0.f, 0.f, 0.f, 0.f};
  float mrow[4], lrow[4];
#pragma unroll
  for (int r = 0; r < 4; ++r) { mrow[r] = -3.0e38f; lrow[r] = 0.f; }

  const float CSC = 0.08838834764831845f * 1.44269504088896f;  // scale*log2e
  const int nkt = qt + 1;

  for (int kt = 0; kt < nkt; ++kt) {
    const int kt0 = kt * 64;
    __syncthreads();
    // stage K tile: 64 rows x 16 chunks
#pragma unroll
    for (int p = 0; p < 4; ++p) {
      int row = p * 16 + (tid >> 4), ch = tid & 15;
      int gch = ch ^ (row & 15);
      gld16(k16 + ((size_t)(kt0 + row) * NKV + kvh) * DH + gch * 8,
            (ushort*)Ks + (p * 256 + w * 64) * 8);
    }
    // stage V^T tile: 128 rows x 8 chunks
#pragma unroll
    for (int p = 0; p < 4; ++p) {
      int row = p * 32 + (tid >> 3), ch = tid & 7;
      int gch = ch ^ (row & 7);
      gld16(v16t + (size_t)(kvh * DH + row) * T_SEQ + kt0 + gch * 8,
            (ushort*)Vs + (p * 256 + w * 64) * 8);
    }
    __syncthreads();

    // S = Q K^T  (A = Q frags, B from Ks)
    f32x4 sacc[4];
#pragma unroll
    for (int ni = 0; ni < 4; ++ni) sacc[ni] = (f32x4){0.f, 0.f, 0.f, 0.f};
#pragma unroll
    for (int ks = 0; ks < 4; ++ks)
#pragma unroll
      for (int ni = 0; ni < 4; ++ni) {
        int row = ni * 16 + l15;
        int pch = (ks * 4 + quad) ^ (row & 15);
        bf16x8 kf = *(const bf16x8*)(Ks + row * 128 + pch * 8);
        sacc[ni] = __builtin_amdgcn_mfma_f32_16x16x32_bf16(
            qf[ks], kf, sacc[ni], 0, 0, 0);
      }

    // mask + scale into log2 domain
    float sc[4][4];
#pragma unroll
    for (int ni = 0; ni < 4; ++ni) {
      int key = kt0 + ni * 16 + l15;
#pragma unroll
      for (int r = 0; r < 4; ++r) {
        int q = q0 + w * 16 + quad * 4 + r;
        sc[ni][r] = (key <= q) ? sacc[ni][r] * CSC : -3.0e38f;
      }
    }
    // online softmax (rows live in 16-lane groups; xor 1,2,4,8)
    float mnew[4], alpha[4], psum[4];
#pragma unroll
    for (int r = 0; r < 4; ++r) {
      float t = fmaxf(fmaxf(sc[0][r], sc[1][r]), fmaxf(sc[2][r], sc[3][r]));
      t = fmaxf(t, __shfl_xor(t, 1, 64));
      t = fmaxf(t, __shfl_xor(t, 2, 64));
      t = fmaxf(t, __shfl_xor(t, 4, 64));
      t = fmaxf(t, __shfl_xor(t, 8, 64));
      mnew[r] = fmaxf(mrow[r], t);
      alpha[r] = exp2f(mrow[r] - mnew[r]);
      mrow[r] = mnew[r];
      psum[r] = 0.f;
    }
#pragma unroll
    for (int ni = 0; ni < 4; ++ni)
#pragma unroll
      for (int r = 0; r < 4; ++r) {
        float p = exp2f(sc[ni][r] - mnew[r]);
        psum[r] += p;
        Ps[w][quad * 4 + r][ni * 16 + l15] = f2bf(p);
      }
#pragma unroll
    for (int r = 0; r < 4; ++r) {
      float s = psum[r];
      s += __shfl_xor(s, 1, 64);
      s += __shfl_xor(s, 2, 64);
      s += __shfl_xor(s, 4, 64);
      s += __shfl_xor(s, 8, 64);
      lrow[r] = lrow[r] * alpha[r] + s;
    }
#pragma unroll
    for (int ni = 0; ni < 8; ++ni)
#pragma unroll
      for (int r = 0; r < 4; ++r) oacc[ni][r] *= alpha[r];

    // O += P V   (A = P from wave-private LDS, B from Vs)
#pragma unroll
    for (int ks2 = 0; ks2 < 2; ++ks2) {
      bf16x8 pf = *(const bf16x8*)(&Ps[w][l15][ks2 * 32 + quad * 8]);
#pragma unroll
      for (int ni = 0; ni < 8; ++ni) {
        int row = ni * 16 + l15;
        int pch = (ks2 * 4 + quad) ^ (row & 7);
        bf16x8 vf = *(const bf16x8*)(Vs + row * 64 + pch * 8);
        oacc[ni] = __builtin_amdgcn_mfma_f32_16x16x32_bf16(
            pf, vf, oacc[ni], 0, 0, 0);
      }
    }
  }

  // epilogue: o = (o/l)*sigmoid(gate) -> ob16[t][h*128+d] (bf16)
  float inv_l[4];
#pragma unroll
  for (int r = 0; r < 4; ++r) inv_l[r] = 1.0f / lrow[r];
#pragma unroll
  for (int ni = 0; ni < 8; ++ni) {
    int d = ni * 16 + l15;
#pragma unroll
    for (int r = 0; r < 4; ++r) {
      int q = q0 + w * 16 + quad * 4 + r;
      float g = bf2f(qg16[((size_t)q * NH + h) * (2 * DH) + DH + d]);
      float o = oacc[ni][r] * inv_l[r];
      o = o / (1.0f + exp2f(-g * 1.44269504088896f));
      ob16[(size_t)q * (NH * DH) + h * DH + d] = f2bf(o);
    }
  }
}

extern "C" void kernel_launch(void* const* d_in, const int* in_sizes, int n_in,
                              void* d_out, int out_size, void* d_ws, size_t ws_size,
                              hipStream_t stream) {
  const int*   positions = (const int*)d_in[0];
  const float* hs  = (const float*)d_in[1];
  const float* Wq  = (const float*)d_in[2];
  const float* Wk  = (const float*)d_in[3];
  const float* Wv  = (const float*)d_in[4];
  const float* Wo  = (const float*)d_in[5];
  const float* qnw = (const float*)d_in[6];
  const float* knw = (const float*)d_in[7];
  float* out = (float*)d_out;

  // workspace layout (60 MB), with region reuse across the pipeline
  const size_t MB = 1 << 20;
  uint8_t* ws = (uint8_t*)d_ws;
  ushort* qg16 = (ushort*)(ws + 0);        // 16MB  [t][h][256] (q | gate)
  ushort* kb16 = (ushort*)(ws + 16 * MB);  //  4MB  [t][kv][128]
  ushort* hs16 = (ushort*)(ws + 20 * MB);  //  8MB  [t][2048]
  ushort* ob16 = (ushort*)(ws + 20 * MB);  //  (reuse after QKV GEMMs)
  ushort* Wqt  = (ushort*)(ws + 28 * MB);  // 16MB  [4096][2048]
  ushort* q16  = (ushort*)(ws + 28 * MB);  //  8MB  (reuse after Q GEMM)
  ushort* k16  = (ushort*)(ws + 36 * MB);  //  4MB
  ushort* v16t = (ushort*)(ws + 40 * MB);  //  4MB  [kv*128][2048]
  ushort* Wkt  = (ushort*)(ws + 44 * MB);  //  4MB
  ushort* v16  = (ushort*)(ws + 44 * MB);  //  (reuse after K GEMM)
  ushort* Wvt  = (ushort*)(ws + 48 * MB);  //  4MB
  ushort* Wot  = (ushort*)(ws + 52 * MB);  //  8MB

  conv_bf16<<<(T_SEQ * HID) / 1024, 256, 0, stream>>>(hs, hs16);
  transpose_to_bf16<float><<<dim3(128, 64), 256, 0, stream>>>(Wq, Wqt, HID, 4096);
  transpose_to_bf16<float><<<dim3(32, 64), 256, 0, stream>>>(Wk, Wkt, HID, 1024);
  transpose_to_bf16<float><<<dim3(32, 64), 256, 0, stream>>>(Wv, Wvt, HID, 1024);
  transpose_to_bf16<float><<<dim3(64, 64), 256, 0, stream>>>(Wo, Wot, HID, 2048);

  gemm_bt<1><<<dim3(32, 16), 256, 0, stream>>>(hs16, Wqt, nullptr, qg16,
                                               T_SEQ, 4096, HID);
  gemm_bt<1><<<dim3(8, 16), 256, 0, stream>>>(hs16, Wkt, nullptr, kb16,
                                              T_SEQ, 1024, HID);
  gemm_bt<1><<<dim3(8, 16), 256, 0, stream>>>(hs16, Wvt, nullptr, v16,
                                              T_SEQ, 1024, HID);
  transpose_to_bf16<ushort><<<dim3(32, 64), 256, 0, stream>>>(v16, v16t,
                                                              T_SEQ, 1024);
  norm_rope<<<dim3(T_SEQ, NH + NKV), 128, 0, stream>>>(qg16, kb16, positions,
                                                       qnw, knw, q16, k16);
  attn_mfma<<<dim3(32, NH), 256, 0, stream>>>(q16, k16, v16t, qg16, ob16);
  gemm_bt<0><<<dim3(16, 16), 256, 0, stream>>>(ob16, Wot, out, nullptr,
                                               T_SEQ, HID, HID);
}

// Round 3
// 328.783 us; speedup vs baseline: 6.1241x; 1.3745x over previous
//
#include <hip/hip_runtime.h>
#include <stdint.h>
#include <math.h>

// Problem constants
#define T_SEQ 2048
#define HID   2048
#define NH    16
#define NKV   8
#define DH    128

typedef __bf16 bf16x8 __attribute__((ext_vector_type(8)));
typedef float  f32x4  __attribute__((ext_vector_type(4)));

__device__ __forceinline__ ushort f2bf(float f) {   // round-to-nearest-even
  uint32_t u = __float_as_uint(f);
  u += 0x7FFF + ((u >> 16) & 1);
  return (ushort)(u >> 16);
}
__device__ __forceinline__ float bf2f(ushort u) {
  return __uint_as_float(((uint32_t)u) << 16);
}
// async global->LDS, 16B per lane; LDS dest = wave-uniform base + lane*16
__device__ __forceinline__ void gld16(const void* g, void* l) {
  __builtin_amdgcn_global_load_lds(
      (const __attribute__((address_space(1))) uint32_t*)g,
      (__attribute__((address_space(3))) uint32_t*)l, 16, 0, 0);
}

// ---------------- prep: hs conv + W transposes + score bound --------------
// flat grid: [0,4096) conv hs; [4096,12288) Wq^T; [12288,14336) Wk^T;
// [14336,16384) Wv^T; block 16384 = bound from norm weights.
__global__ __launch_bounds__(256) void prep_kernel(
    const float* __restrict__ hs, const float* __restrict__ Wq,
    const float* __restrict__ Wk, const float* __restrict__ Wv,
    const float* __restrict__ qnw, const float* __restrict__ knw,
    ushort* __restrict__ hs16, ushort* __restrict__ Wqt,
    ushort* __restrict__ Wkt, ushort* __restrict__ Wvt,
    float* __restrict__ bnd) {
  int bid = blockIdx.x;
  if (bid < 4096) {  // conv hs -> bf16
    int i = (bid * 256 + threadIdx.x) * 4;
    float4 v = *(const float4*)(hs + i);
    ushort4 o = {f2bf(v.x), f2bf(v.y), f2bf(v.z), f2bf(v.w)};
    *(ushort4*)(hs16 + i) = o;
    return;
  }
  if (bid == 16384) {  // score upper bound (log2 domain)
    int t = threadIdx.x;
    if (t >= 128) return;
    float mq = fabsf(1.f + qnw[t]);
    float mk = fabsf(1.f + knw[t]);
#pragma unroll
    for (int off = 32; off >= 1; off >>= 1) {
      mq = fmaxf(mq, __shfl_xor(mq, off, 64));
      mk = fmaxf(mk, __shfl_xor(mk, off, 64));
    }
    __shared__ float s4[4];
    if ((t & 63) == 0) { s4[(t >> 6) * 2] = mq; s4[(t >> 6) * 2 + 1] = mk; }
    __syncthreads();
    if (t == 0) {
      float MQ = fmaxf(s4[0], s4[2]), MK = fmaxf(s4[1], s4[3]);
      // sqrt(128)*log2(e) = 16.3217; 2% + 0.1 safety margin
      bnd[0] = 16.3217f * MQ * MK * 1.02f + 0.1f;
    }
    return;
  }
  bid -= 4096;
  const float* src; ushort* dst; int N, bi, bj;
  if (bid < 8192)       { src = Wq; dst = Wqt; N = 4096; bj = bid & 127; bi = bid >> 7; }
  else if (bid < 10240) { bid -= 8192;  src = Wk; dst = Wkt; N = 1024; bj = bid & 31; bi = bid >> 5; }
  else                  { bid -= 10240; src = Wv; dst = Wvt; N = 1024; bj = bid & 31; bi = bid >> 5; }
  __shared__ float tile[32][33];
  int row = threadIdx.x >> 3, c4 = (threadIdx.x & 7) * 4;
  float4 v = *(const float4*)(src + (size_t)(bi * 32 + row) * N + bj * 32 + c4);
  tile[row][c4 + 0] = v.x; tile[row][c4 + 1] = v.y;
  tile[row][c4 + 2] = v.z; tile[row][c4 + 3] = v.w;
  __syncthreads();
  ushort4 o = {f2bf(tile[c4 + 0][row]), f2bf(tile[c4 + 1][row]),
               f2bf(tile[c4 + 2][row]), f2bf(tile[c4 + 3][row])};
  *(ushort4*)(dst + (size_t)(bj * 32 + row) * HID + bi * 32 + c4) = o;
}

// ---------------- Wo transpose (runs late, into freed region) -------------
__global__ __launch_bounds__(256) void prep_wo(const float* __restrict__ Wo,
                                               ushort* __restrict__ Wot) {
  int bid = blockIdx.x;
  int bj = bid & 63, bi = bid >> 6;
  __shared__ float tile[32][33];
  int row = threadIdx.x >> 3, c4 = (threadIdx.x & 7) * 4;
  float4 v = *(const float4*)(Wo + (size_t)(bi * 32 + row) * HID + bj * 32 + c4);
  tile[row][c4 + 0] = v.x; tile[row][c4 + 1] = v.y;
  tile[row][c4 + 2] = v.z; tile[row][c4 + 3] = v.w;
  __syncthreads();
  ushort4 o = {f2bf(tile[c4 + 0][row]), f2bf(tile[c4 + 1][row]),
               f2bf(tile[c4 + 2][row]), f2bf(tile[c4 + 3][row])};
  *(ushort4*)(Wot + (size_t)(bj * 32 + row) * HID + bi * 32 + c4) = o;
}

// ---------------- bf16 MFMA GEMM core: C[m0:,n0:] = A @ Bt^T --------------
template <int OUT_BF16>
__device__ __forceinline__ void gemm_core(
    const ushort* __restrict__ A, const ushort* __restrict__ Bt,
    float* __restrict__ Cf, ushort* __restrict__ Cb, int N, int K,
    int m0, int n0, ushort* As, ushort* Bs) {
  const int tid = threadIdx.x, lane = tid & 63, w = tid >> 6;
  const int quad = lane >> 4, l15 = lane & 15;
  const int wm = (w >> 1) * 64, wn = (w & 1) * 64;
  f32x4 acc[4][4];
#pragma unroll
  for (int i = 0; i < 4; ++i)
#pragma unroll
    for (int j = 0; j < 4; ++j) acc[i][j] = (f32x4){0.f, 0.f, 0.f, 0.f};

  const int srow = tid >> 2, sch = tid & 3;
  for (int k0 = 0; k0 < K; k0 += 32) {
    __syncthreads();
#pragma unroll
    for (int p = 0; p < 2; ++p) {
      int row = p * 64 + srow;
      int gch = sch ^ ((row >> 1) & 3);
      gld16(A + (size_t)(m0 + row) * K + k0 + gch * 8,
            As + (p * 256 + w * 64) * 8);
      gld16(Bt + (size_t)(n0 + row) * K + k0 + gch * 8,
            Bs + (p * 256 + w * 64) * 8);
    }
    __syncthreads();
    bf16x8 af[4], bfr[4];
#pragma unroll
    for (int mi = 0; mi < 4; ++mi) {
      int row = wm + mi * 16 + l15;
      int pch = quad ^ ((row >> 1) & 3);
      af[mi] = *(const bf16x8*)(As + row * 32 + pch * 8);
    }
#pragma unroll
    for (int ni = 0; ni < 4; ++ni) {
      int row = wn + ni * 16 + l15;
      int pch = quad ^ ((row >> 1) & 3);
      bfr[ni] = *(const bf16x8*)(Bs + row * 32 + pch * 8);
    }
#pragma unroll
    for (int mi = 0; mi < 4; ++mi)
#pragma unroll
      for (int ni = 0; ni < 4; ++ni)
        acc[mi][ni] = __builtin_amdgcn_mfma_f32_16x16x32_bf16(
            af[mi], bfr[ni], acc[mi][ni], 0, 0, 0);
  }
  // C/D layout: col = lane&15, row = quad*4 + reg
#pragma unroll
  for (int mi = 0; mi < 4; ++mi)
#pragma unroll
    for (int ni = 0; ni < 4; ++ni)
#pragma unroll
      for (int r = 0; r < 4; ++r) {
        int row = m0 + wm + mi * 16 + quad * 4 + r;
        int col = n0 + wn + ni * 16 + l15;
        if (OUT_BF16) Cb[(size_t)row * N + col] = f2bf(acc[mi][ni][r]);
        else          Cf[(size_t)row * N + col] = acc[mi][ni][r];
      }
}

// Fused QKV projections. [0,512): Q -> qg16; [512,640): K -> kb16;
// [640,768): V^T = Wvt @ hs16^T -> v16t (no separate transpose pass).
__global__ __launch_bounds__(256) void gemm_qkv(
    const ushort* __restrict__ hs16, const ushort* __restrict__ Wqt,
    const ushort* __restrict__ Wkt, const ushort* __restrict__ Wvt,
    ushort* __restrict__ qg16, ushort* __restrict__ kb16,
    ushort* __restrict__ v16t) {
  __shared__ ushort As[128 * 32];
  __shared__ ushort Bs[128 * 32];
  int b = blockIdx.x;
  if (b < 512) {
    gemm_core<1>(hs16, Wqt, nullptr, qg16, 4096, HID, (b >> 5) * 128,
                 (b & 31) * 128, As, Bs);
  } else if (b < 640) {
    int f = b - 512;
    gemm_core<1>(hs16, Wkt, nullptr, kb16, 1024, HID, (f >> 3) * 128,
                 (f & 7) * 128, As, Bs);
  } else {
    int f = b - 640;
    gemm_core<1>(Wvt, hs16, nullptr, v16t, 2048, HID, (f >> 4) * 128,
                 (f & 15) * 128, As, Bs);
  }
}

__global__ __launch_bounds__(256) void gemm_out(
    const ushort* __restrict__ ob16, const ushort* __restrict__ Wot,
    float* __restrict__ out) {
  __shared__ ushort As[128 * 32];
  __shared__ ushort Bs[128 * 32];
  int b = blockIdx.x;
  gemm_core<0>(ob16, Wot, out, nullptr, HID, HID, (b >> 4) * 128,
               (b & 15) * 128, As, Bs);
}

// ---------------- RMSNorm + RoPE (bf16 in -> bf16 out) --------------------
__global__ __launch_bounds__(128) void norm_rope(
    const ushort* __restrict__ qg16, const ushort* __restrict__ kb16,
    const int* __restrict__ positions, const float* __restrict__ qw,
    const float* __restrict__ kw, ushort* __restrict__ q16,
    ushort* __restrict__ k16) {
  const int t = blockIdx.x, hh = blockIdx.y, d = threadIdx.x;
  const ushort* x; const float* wgt; ushort* out;
  if (hh < NH) {
    x = qg16 + ((size_t)t * NH + hh) * (2 * DH); wgt = qw;
    out = q16 + ((size_t)t * NH + hh) * DH;
  } else {
    x = kb16 + ((size_t)t * NKV + (hh - NH)) * DH; wgt = kw;
    out = k16 + ((size_t)t * NKV + (hh - NH)) * DH;
  }
  float v = bf2f(x[d]);
  float ss = v * v;
#pragma unroll
  for (int off = 32; off >= 1; off >>= 1) ss += __shfl_xor(ss, off, 64);
  __shared__ float red[2];
  if ((d & 63) == 0) red[d >> 6] = ss;
  __syncthreads();
  float mean = (red[0] + red[1]) * (1.0f / 128.0f);
  float xn = v * rsqrtf(mean + 1e-6f) * (1.0f + wgt[d]);
  __shared__ float sh[128];
  sh[d] = xn;
  __syncthreads();
  if (d < 64) {
    float pos = (float)positions[t];
    float freq = pos * exp2f(-(float)d * (13.287712379549449f / 64.0f));
    float s, c;
    sincosf(freq, &s, &c);
    float x1 = sh[d], x2 = sh[d + 64];
    out[d]      = f2bf(x1 * c - x2 * s);
    out[d + 64] = f2bf(x2 * c + x1 * s);
  }
}

// ---------------- MFMA flash attention, static-bound softmax --------------
// grid (16, NH): block pb processes q-tiles {pb, 31-pb} sequentially ->
// every block does exactly 33 k-tile iterations (perfect balance).
// Double-buffered K/V staging. p = exp2(s*c - B): no running max, no
// rescale. Row-sum l comes free from a ones-column in V^T (tile ni=8).
__global__ __launch_bounds__(256) void attn_mfma(
    const ushort* __restrict__ q16, const ushort* __restrict__ k16,
    const ushort* __restrict__ v16t, const ushort* __restrict__ qg16,
    const float* __restrict__ bnd, ushort* __restrict__ ob16) {
  const int pb = blockIdx.x, h = blockIdx.y, kvh = h >> 1;
  const int tid = threadIdx.x, lane = tid & 63, w = tid >> 6;
  const int quad = lane >> 4, l15 = lane & 15;

  __shared__ ushort Ks[2][64 * 128];
  __shared__ ushort Vs[2][144 * 64];   // rows 128..143: ones row + zeros
  __shared__ ushort Ps[4][16][72];

  // init constant rows of Vs (row 128 = 1.0, 129..143 = 0); staged K/V only
  // ever writes rows 0..127, so this survives all iterations.
#pragma unroll
  for (int buf = 0; buf < 2; ++buf)
    for (int i = tid; i < 16 * 64; i += 256) {
      int row = 128 + (i >> 6), col = i & 63;
      Vs[buf][row * 64 + col] = (row == 128) ? (ushort)0x3F80 : (ushort)0;
    }

  const float B = bnd[0];
  const float CSC = 0.08838834764831845f * 1.44269504088896f;  // scale*log2e

#pragma unroll 1
  for (int sel = 0; sel < 2; ++sel) {
    const int qt = sel ? (31 - pb) : pb;
    const int q0 = qt * 64, nk = qt + 1;

    bf16x8 qf[4];
    const ushort* qbase = q16 + ((size_t)(q0 + w * 16 + l15) * NH + h) * DH;
#pragma unroll
    for (int ks = 0; ks < 4; ++ks)
      qf[ks] = *(const bf16x8*)(qbase + ks * 32 + quad * 8);

    f32x4 oacc[9];
#pragma unroll
    for (int i = 0; i < 9; ++i) oacc[i] = (f32x4){0.f, 0.f, 0.f, 0.f};

    __syncthreads();  // prior q-tile's buffer readers done before restage
    // stage kt=0 into buf 0
    {
#pragma unroll
      for (int p = 0; p < 4; ++p) {
        int row = p * 16 + (tid >> 4), ch = tid & 15;
        int gch = ch ^ (row & 15);
        gld16(k16 + ((size_t)row * NKV + kvh) * DH + gch * 8,
              (ushort*)Ks[0] + (p * 256 + w * 64) * 8);
      }
#pragma unroll
      for (int p = 0; p < 4; ++p) {
        int row = p * 32 + (tid >> 3), ch = tid & 7;
        int gch = ch ^ (row & 7);
        gld16(v16t + (size_t)(kvh * DH + row) * T_SEQ + gch * 8,
              (ushort*)Vs[0] + (p * 256 + w * 64) * 8);
      }
    }

#pragma unroll 1
    for (int kt = 0; kt < nk; ++kt) {
      const int cur = kt & 1;
      __syncthreads();  // staged buf[cur] landed; prior reads of buf[!cur] done
      if (kt + 1 < nk) {  // prefetch next tile; flies during compute below
        const int nt0 = (kt + 1) * 64;
#pragma unroll
        for (int p = 0; p < 4; ++p) {
          int row = p * 16 + (tid >> 4), ch = tid & 15;
          int gch = ch ^ (row & 15);
          gld16(k16 + ((size_t)(nt0 + row) * NKV + kvh) * DH + gch * 8,
                (ushort*)Ks[1 - cur] + (p * 256 + w * 64) * 8);
        }
#pragma unroll
        for (int p = 0; p < 4; ++p) {
          int row = p * 32 + (tid >> 3), ch = tid & 7;
          int gch = ch ^ (row & 7);
          gld16(v16t + (size_t)(kvh * DH + row) * T_SEQ + nt0 + gch * 8,
                (ushort*)Vs[1 - cur] + (p * 256 + w * 64) * 8);
        }
      }

      // S = Q K^T
      f32x4 sacc[4];
#pragma unroll
      for (int ni = 0; ni < 4; ++ni) sacc[ni] = (f32x4){0.f, 0.f, 0.f, 0.f};
      const ushort* KsC = Ks[cur];
#pragma unroll
      for (int ks = 0; ks < 4; ++ks)
#pragma unroll
        for (int ni = 0; ni < 4; ++ni) {
          int row = ni * 16 + l15;
          int pch = (ks * 4 + quad) ^ (row & 15);
          bf16x8 kf = *(const bf16x8*)(KsC + row * 128 + pch * 8);
          sacc[ni] = __builtin_amdgcn_mfma_f32_16x16x32_bf16(
              qf[ks], kf, sacc[ni], 0, 0, 0);
        }

      // p = exp2(s*CSC - B); mask only on the diagonal tile
      const bool diag = (kt == qt);
      const int kt0 = kt * 64;
#pragma unroll
      for (int ni = 0; ni < 4; ++ni) {
        int key = kt0 + ni * 16 + l15;
#pragma unroll
        for (int r = 0; r < 4; ++r) {
          float arg = fmaf(sacc[ni][r], CSC, -B);
          float pv;
          if (diag) {
            int q = q0 + w * 16 + quad * 4 + r;
            pv = (key <= q) ? exp2f(arg) : 0.f;
          } else {
            pv = exp2f(arg);
          }
          Ps[w][quad * 4 + r][ni * 16 + l15] = f2bf(pv);
        }
      }

      // O += P V  (ni=8 tile: ones column -> row-sums accumulate in col 0)
      const ushort* VsC = Vs[cur];
#pragma unroll
      for (int ks2 = 0; ks2 < 2; ++ks2) {
        bf16x8 pf = *(const bf16x8*)(&Ps[w][l15][ks2 * 32 + quad * 8]);
#pragma unroll
        for (int ni = 0; ni < 9; ++ni) {
          int row = ni * 16 + l15;
          int pch = (ks2 * 4 + quad) ^ (row & 7);
          bf16x8 vf = *(const bf16x8*)(VsC + row * 64 + pch * 8);
          oacc[ni] = __builtin_amdgcn_mfma_f32_16x16x32_bf16(
              pf, vf, oacc[ni], 0, 0, 0);
        }
      }
    }

    // epilogue: l lives in lane (quad*16) of the ni=8 accumulator
    float inv_l[4];
#pragma unroll
    for (int r = 0; r < 4; ++r) {
      float l = __shfl(oacc[8][r], lane & 48, 64);
      inv_l[r] = 1.0f / l;
    }
#pragma unroll
    for (int ni = 0; ni < 8; ++ni) {
      int d = ni * 16 + l15;
#pragma unroll
      for (int r = 0; r < 4; ++r) {
        int q = q0 + w * 16 + quad * 4 + r;
        float g = bf2f(qg16[((size_t)q * NH + h) * (2 * DH) + DH + d]);
        float o = oacc[ni][r] * inv_l[r];
        o = o / (1.0f + exp2f(-g * 1.44269504088896f));
        ob16[(size_t)q * (NH * DH) + h * DH + d] = f2bf(o);
      }
    }
  }
}

extern "C" void kernel_launch(void* const* d_in, const int* in_sizes, int n_in,
                              void* d_out, int out_size, void* d_ws, size_t ws_size,
                              hipStream_t stream) {
  const int*   positions = (const int*)d_in[0];
  const float* hs  = (const float*)d_in[1];
  const float* Wq  = (const float*)d_in[2];
  const float* Wk  = (const float*)d_in[3];
  const float* Wv  = (const float*)d_in[4];
  const float* Wo  = (const float*)d_in[5];
  const float* qnw = (const float*)d_in[6];
  const float* knw = (const float*)d_in[7];
  float* out = (float*)d_out;

  // workspace layout (56MB + 4B), regions reused across pipeline stages
  const size_t MB = 1 << 20;
  uint8_t* ws = (uint8_t*)d_ws;
  ushort* qg16 = (ushort*)(ws + 0);        // 16MB [t][h][256] (q|gate), ->attn
  ushort* kb16 = (ushort*)(ws + 16 * MB);  //  4MB [t][kv][128], ->norm_rope
  ushort* hs16 = (ushort*)(ws + 20 * MB);  //  8MB, ->gemm_qkv
  ushort* ob16 = (ushort*)(ws + 20 * MB);  //  8MB (reuse), attn->gemm_out
  ushort* Wqt  = (ushort*)(ws + 28 * MB);  // 16MB, ->gemm_qkv
  ushort* q16  = (ushort*)(ws + 28 * MB);  //  8MB (reuse), norm->attn
  ushort* Wot  = (ushort*)(ws + 36 * MB);  //  8MB (reuse), prep_wo->gemm_out
  ushort* Wkt  = (ushort*)(ws + 44 * MB);  //  4MB, ->gemm_qkv
  ushort* k16  = (ushort*)(ws + 44 * MB);  //  4MB (reuse), norm->attn
  ushort* Wvt  = (ushort*)(ws + 48 * MB);  //  4MB, ->gemm_qkv
  ushort* v16t = (ushort*)(ws + 52 * MB);  //  4MB [kv*128][t], ->attn
  float*  bnd  = (float*)(ws + 56 * MB);   //  4B

  prep_kernel<<<16385, 256, 0, stream>>>(hs, Wq, Wk, Wv, qnw, knw,
                                         hs16, Wqt, Wkt, Wvt, bnd);
  gemm_qkv<<<768, 256, 0, stream>>>(hs16, Wqt, Wkt, Wvt, qg16, kb16, v16t);
  norm_rope<<<dim3(T_SEQ, NH + NKV), 128, 0, stream>>>(qg16, kb16, positions,
                                                       qnw, knw, q16, k16);
  prep_wo<<<4096, 256, 0, stream>>>(Wo, Wot);
  attn_mfma<<<dim3(16, NH), 256, 0, stream>>>(q16, k16, v16t, qg16, bnd, ob16);
  gemm_out<<<256, 256, 0, stream>>>(ob16, Wot, out);
}

// Round 4
// 301.431 us; speedup vs baseline: 6.6798x; 1.0907x over previous
//
#include <hip/hip_runtime.h>
#include <stdint.h>
#include <math.h>

// Problem constants
#define T_SEQ 2048
#define HID   2048
#define NH    16
#define NKV   8
#define DH    128

typedef __bf16 bf16x8 __attribute__((ext_vector_type(8)));
typedef float  f32x4  __attribute__((ext_vector_type(4)));

__device__ __forceinline__ ushort f2bf(float f) {   // round-to-nearest-even
  uint32_t u = __float_as_uint(f);
  u += 0x7FFF + ((u >> 16) & 1);
  return (ushort)(u >> 16);
}
__device__ __forceinline__ float bf2f(ushort u) {
  return __uint_as_float(((uint32_t)u) << 16);
}
// async global->LDS, 16B per lane; LDS dest = wave-uniform base + lane*16
__device__ __forceinline__ void gld16(const void* g, void* l) {
  __builtin_amdgcn_global_load_lds(
      (const __attribute__((address_space(1))) uint32_t*)g,
      (__attribute__((address_space(3))) uint32_t*)l, 16, 0, 0);
}

// ---------------- prep: hs conv + W transposes ----------------------------
// flat grid: [0,4096) conv hs; [4096,12288) Wq^T; [12288,14336) Wk^T;
// [14336,16384) Wv^T.
__global__ __launch_bounds__(256) void prep_kernel(
    const float* __restrict__ hs, const float* __restrict__ Wq,
    const float* __restrict__ Wk, const float* __restrict__ Wv,
    ushort* __restrict__ hs16, ushort* __restrict__ Wqt,
    ushort* __restrict__ Wkt, ushort* __restrict__ Wvt) {
  int bid = blockIdx.x;
  if (bid < 4096) {  // conv hs -> bf16
    int i = (bid * 256 + threadIdx.x) * 4;
    float4 v = *(const float4*)(hs + i);
    ushort4 o = {f2bf(v.x), f2bf(v.y), f2bf(v.z), f2bf(v.w)};
    *(ushort4*)(hs16 + i) = o;
    return;
  }
  bid -= 4096;
  const float* src; ushort* dst; int N, bi, bj;
  if (bid < 8192)       { src = Wq; dst = Wqt; N = 4096; bj = bid & 127; bi = bid >> 7; }
  else if (bid < 10240) { bid -= 8192;  src = Wk; dst = Wkt; N = 1024; bj = bid & 31; bi = bid >> 5; }
  else                  { bid -= 10240; src = Wv; dst = Wvt; N = 1024; bj = bid & 31; bi = bid >> 5; }
  __shared__ float tile[32][33];
  int row = threadIdx.x >> 3, c4 = (threadIdx.x & 7) * 4;
  float4 v = *(const float4*)(src + (size_t)(bi * 32 + row) * N + bj * 32 + c4);
  tile[row][c4 + 0] = v.x; tile[row][c4 + 1] = v.y;
  tile[row][c4 + 2] = v.z; tile[row][c4 + 3] = v.w;
  __syncthreads();
  ushort4 o = {f2bf(tile[c4 + 0][row]), f2bf(tile[c4 + 1][row]),
               f2bf(tile[c4 + 2][row]), f2bf(tile[c4 + 3][row])};
  *(ushort4*)(dst + (size_t)(bj * 32 + row) * HID + bi * 32 + c4) = o;
}

// ---------------- Wo transpose (runs late, into freed region) -------------
__global__ __launch_bounds__(256) void prep_wo(const float* __restrict__ Wo,
                                               ushort* __restrict__ Wot) {
  int bid = blockIdx.x;
  int bj = bid & 63, bi = bid >> 6;
  __shared__ float tile[32][33];
  int row = threadIdx.x >> 3, c4 = (threadIdx.x & 7) * 4;
  float4 v = *(const float4*)(Wo + (size_t)(bi * 32 + row) * HID + bj * 32 + c4);
  tile[row][c4 + 0] = v.x; tile[row][c4 + 1] = v.y;
  tile[row][c4 + 2] = v.z; tile[row][c4 + 3] = v.w;
  __syncthreads();
  ushort4 o = {f2bf(tile[c4 + 0][row]), f2bf(tile[c4 + 1][row]),
               f2bf(tile[c4 + 2][row]), f2bf(tile[c4 + 3][row])};
  *(ushort4*)(Wot + (size_t)(bj * 32 + row) * HID + bi * 32 + c4) = o;
}

// ---------------- bf16 MFMA GEMM core: C[m0:,n0:] = A @ Bt^T --------------
template <int OUT_BF16>
__device__ __forceinline__ void gemm_core(
    const ushort* __restrict__ A, const ushort* __restrict__ Bt,
    float* __restrict__ Cf, ushort* __restrict__ Cb, int N, int K,
    int m0, int n0, ushort* As, ushort* Bs) {
  const int tid = threadIdx.x, lane = tid & 63, w = tid >> 6;
  const int quad = lane >> 4, l15 = lane & 15;
  const int wm = (w >> 1) * 64, wn = (w & 1) * 64;
  f32x4 acc[4][4];
#pragma unroll
  for (int i = 0; i < 4; ++i)
#pragma unroll
    for (int j = 0; j < 4; ++j) acc[i][j] = (f32x4){0.f, 0.f, 0.f, 0.f};

  const int srow = tid >> 2, sch = tid & 3;
  for (int k0 = 0; k0 < K; k0 += 32) {
    __syncthreads();
#pragma unroll
    for (int p = 0; p < 2; ++p) {
      int row = p * 64 + srow;
      int gch = sch ^ ((row >> 1) & 3);
      gld16(A + (size_t)(m0 + row) * K + k0 + gch * 8,
            As + (p * 256 + w * 64) * 8);
      gld16(Bt + (size_t)(n0 + row) * K + k0 + gch * 8,
            Bs + (p * 256 + w * 64) * 8);
    }
    __syncthreads();
    bf16x8 af[4], bfr[4];
#pragma unroll
    for (int mi = 0; mi < 4; ++mi) {
      int row = wm + mi * 16 + l15;
      int pch = quad ^ ((row >> 1) & 3);
      af[mi] = *(const bf16x8*)(As + row * 32 + pch * 8);
    }
#pragma unroll
    for (int ni = 0; ni < 4; ++ni) {
      int row = wn + ni * 16 + l15;
      int pch = quad ^ ((row >> 1) & 3);
      bfr[ni] = *(const bf16x8*)(Bs + row * 32 + pch * 8);
    }
#pragma unroll
    for (int mi = 0; mi < 4; ++mi)
#pragma unroll
      for (int ni = 0; ni < 4; ++ni)
        acc[mi][ni] = __builtin_amdgcn_mfma_f32_16x16x32_bf16(
            af[mi], bfr[ni], acc[mi][ni], 0, 0, 0);
  }
  // C/D layout: col = lane&15, row = quad*4 + reg
#pragma unroll
  for (int mi = 0; mi < 4; ++mi)
#pragma unroll
    for (int ni = 0; ni < 4; ++ni)
#pragma unroll
      for (int r = 0; r < 4; ++r) {
        int row = m0 + wm + mi * 16 + quad * 4 + r;
        int col = n0 + wn + ni * 16 + l15;
        if (OUT_BF16) Cb[(size_t)row * N + col] = f2bf(acc[mi][ni][r]);
        else          Cf[(size_t)row * N + col] = acc[mi][ni][r];
      }
}

// Fused QKV projections. [0,512): Q -> qg16; [512,640): K -> kb16;
// [640,768): V^T = Wvt @ hs16^T -> v16t (no separate transpose pass).
__global__ __launch_bounds__(256) void gemm_qkv(
    const ushort* __restrict__ hs16, const ushort* __restrict__ Wqt,
    const ushort* __restrict__ Wkt, const ushort* __restrict__ Wvt,
    ushort* __restrict__ qg16, ushort* __restrict__ kb16,
    ushort* __restrict__ v16t) {
  __shared__ ushort As[128 * 32];
  __shared__ ushort Bs[128 * 32];
  int b = blockIdx.x;
  if (b < 512) {
    gemm_core<1>(hs16, Wqt, nullptr, qg16, 4096, HID, (b >> 5) * 128,
                 (b & 31) * 128, As, Bs);
  } else if (b < 640) {
    int f = b - 512;
    gemm_core<1>(hs16, Wkt, nullptr, kb16, 1024, HID, (f >> 3) * 128,
                 (f & 7) * 128, As, Bs);
  } else {
    int f = b - 640;
    gemm_core<1>(Wvt, hs16, nullptr, v16t, 2048, HID, (f >> 4) * 128,
                 (f & 15) * 128, As, Bs);
  }
}

__global__ __launch_bounds__(256) void gemm_out(
    const ushort* __restrict__ ob16, const ushort* __restrict__ Wot,
    float* __restrict__ out) {
  __shared__ ushort As[128 * 32];
  __shared__ ushort Bs[128 * 32];
  int b = blockIdx.x;
  gemm_core<0>(ob16, Wot, out, nullptr, HID, HID, (b >> 4) * 128,
               (b & 15) * 128, As, Bs);
}

// ---------------- RMSNorm + RoPE (bf16 in -> bf16 out) --------------------
__global__ __launch_bounds__(128) void norm_rope(
    const ushort* __restrict__ qg16, const ushort* __restrict__ kb16,
    const int* __restrict__ positions, const float* __restrict__ qw,
    const float* __restrict__ kw, ushort* __restrict__ q16,
    ushort* __restrict__ k16) {
  const int t = blockIdx.x, hh = blockIdx.y, d = threadIdx.x;
  const ushort* x; const float* wgt; ushort* out;
  if (hh < NH) {
    x = qg16 + ((size_t)t * NH + hh) * (2 * DH); wgt = qw;
    out = q16 + ((size_t)t * NH + hh) * DH;
  } else {
    x = kb16 + ((size_t)t * NKV + (hh - NH)) * DH; wgt = kw;
    out = k16 + ((size_t)t * NKV + (hh - NH)) * DH;
  }
  float v = bf2f(x[d]);
  float ss = v * v;
#pragma unroll
  for (int off = 32; off >= 1; off >>= 1) ss += __shfl_xor(ss, off, 64);
  __shared__ float red[2];
  if ((d & 63) == 0) red[d >> 6] = ss;
  __syncthreads();
  float mean = (red[0] + red[1]) * (1.0f / 128.0f);
  float xn = v * rsqrtf(mean + 1e-6f) * (1.0f + wgt[d]);
  __shared__ float sh[128];
  sh[d] = xn;
  __syncthreads();
  if (d < 64) {
    float pos = (float)positions[t];
    float freq = pos * exp2f(-(float)d * (13.287712379549449f / 64.0f));
    float s, c;
    sincosf(freq, &s, &c);
    float x1 = sh[d], x2 = sh[d + 64];
    out[d]      = f2bf(x1 * c - x2 * s);
    out[d + 64] = f2bf(x2 * c + x1 * s);
  }
}

// ---------------- MFMA flash attention, key-split x2 ----------------------
// grid (16, NH, 2): block (pb,h,s) processes q-tiles {pb, 31-pb}, k-tiles
// kt ≡ s (mod 2). Every block does 16 or 17 iterations (balanced).
// No running max (static bound B), so partial O/l are summable across the
// two splits; partials stored bf16 + fp32 l, combined by combine_kernel.
__global__ __launch_bounds__(256) void attn_mfma(
    const ushort* __restrict__ q16, const ushort* __restrict__ k16,
    const ushort* __restrict__ v16t, const float* __restrict__ qnw,
    const float* __restrict__ knw, ushort* __restrict__ Op0,
    ushort* __restrict__ Op1, float* __restrict__ lpart) {
  const int pb = blockIdx.x, h = blockIdx.y, s = blockIdx.z, kvh = h >> 1;
  const int tid = threadIdx.x, lane = tid & 63, w = tid >> 6;
  const int quad = lane >> 4, l15 = lane & 15;

  __shared__ ushort Ks[2][64 * 128];
  __shared__ ushort Vs[2][144 * 64];   // rows 128..143: ones row + zeros
  __shared__ ushort Ps[4][16][72];

  // init constant rows of Vs (row 128 = 1.0, 129..143 = 0); staging only
  // writes rows 0..127, so this survives all iterations.
#pragma unroll
  for (int buf = 0; buf < 2; ++buf)
    for (int i = tid; i < 16 * 64; i += 256) {
      int row = 128 + (i >> 6), col = i & 63;
      Vs[buf][row * 64 + col] = (row == 128) ? (ushort)0x3F80 : (ushort)0;
    }

  // score bound B (log2 domain), computed redundantly per block (cheap)
  __shared__ float s8[8];
  __shared__ float bshare;
  {
    float mq = 0.f, mk = 0.f;
    if (tid < 128) { mq = fabsf(1.f + qnw[tid]); mk = fabsf(1.f + knw[tid]); }
#pragma unroll
    for (int off = 32; off >= 1; off >>= 1) {
      mq = fmaxf(mq, __shfl_xor(mq, off, 64));
      mk = fmaxf(mk, __shfl_xor(mk, off, 64));
    }
    if (lane == 0) { s8[w * 2] = mq; s8[w * 2 + 1] = mk; }
    __syncthreads();
    if (tid == 0) {
      float MQ = fmaxf(s8[0], s8[2]), MK = fmaxf(s8[1], s8[3]);
      // sqrt(128)*log2(e) = 16.3217; 2% + 0.1 safety margin
      bshare = 16.3217f * MQ * MK * 1.02f + 0.1f;
    }
    __syncthreads();
  }
  const float B = bshare;
  const float CSC = 0.08838834764831845f * 1.44269504088896f;  // scale*log2e

#pragma unroll 1
  for (int sel = 0; sel < 2; ++sel) {
    const int qt = sel ? (31 - pb) : pb;
    const int q0 = qt * 64, nk = qt + 1;
    const int ntl = (nk > s) ? ((nk - s + 1) >> 1) : 0;  // tiles s, s+2, ...

    bf16x8 qf[4];
    const ushort* qbase = q16 + ((size_t)(q0 + w * 16 + l15) * NH + h) * DH;
#pragma unroll
    for (int ks = 0; ks < 4; ++ks)
      qf[ks] = *(const bf16x8*)(qbase + ks * 32 + quad * 8);

    f32x4 oacc[9];
#pragma unroll
    for (int i = 0; i < 9; ++i) oacc[i] = (f32x4){0.f, 0.f, 0.f, 0.f};

    __syncthreads();  // prior q-tile's buffer readers done before restage
    if (ntl > 0) {    // stage first tile (kt = s) into buf 0
      const int kt0 = s * 64;
#pragma unroll
      for (int p = 0; p < 4; ++p) {
        int row = p * 16 + (tid >> 4), ch = tid & 15;
        int gch = ch ^ (row & 15);
        gld16(k16 + ((size_t)(kt0 + row) * NKV + kvh) * DH + gch * 8,
              (ushort*)Ks[0] + (p * 256 + w * 64) * 8);
      }
#pragma unroll
      for (int p = 0; p < 4; ++p) {
        int row = p * 32 + (tid >> 3), ch = tid & 7;
        int gch = ch ^ (row & 7);
        gld16(v16t + (size_t)(kvh * DH + row) * T_SEQ + kt0 + gch * 8,
              (ushort*)Vs[0] + (p * 256 + w * 64) * 8);
      }
    }

#pragma unroll 1
    for (int it = 0; it < ntl; ++it) {
      const int kt = s + 2 * it;
      const int cur = it & 1;
      __syncthreads();  // staged buf[cur] landed; prior reads of buf[!cur] done
      if (it + 1 < ntl) {  // prefetch tile kt+2; flies during compute below
        const int nt0 = (kt + 2) * 64;
#pragma unroll
        for (int p = 0; p < 4; ++p) {
          int row = p * 16 + (tid >> 4), ch = tid & 15;
          int gch = ch ^ (row & 15);
          gld16(k16 + ((size_t)(nt0 + row) * NKV + kvh) * DH + gch * 8,
                (ushort*)Ks[1 - cur] + (p * 256 + w * 64) * 8);
        }
#pragma unroll
        for (int p = 0; p < 4; ++p) {
          int row = p * 32 + (tid >> 3), ch = tid & 7;
          int gch = ch ^ (row & 7);
          gld16(v16t + (size_t)(kvh * DH + row) * T_SEQ + nt0 + gch * 8,
                (ushort*)Vs[1 - cur] + (p * 256 + w * 64) * 8);
        }
      }

      // S = Q K^T
      f32x4 sacc[4];
#pragma unroll
      for (int ni = 0; ni < 4; ++ni) sacc[ni] = (f32x4){0.f, 0.f, 0.f, 0.f};
      const ushort* KsC = Ks[cur];
#pragma unroll
      for (int ks = 0; ks < 4; ++ks)
#pragma unroll
        for (int ni = 0; ni < 4; ++ni) {
          int row = ni * 16 + l15;
          int pch = (ks * 4 + quad) ^ (row & 15);
          bf16x8 kf = *(const bf16x8*)(KsC + row * 128 + pch * 8);
          sacc[ni] = __builtin_amdgcn_mfma_f32_16x16x32_bf16(
              qf[ks], kf, sacc[ni], 0, 0, 0);
        }

      // p = exp2(s*CSC - B); mask only on the diagonal tile
      const bool diag = (kt == qt);
      const int kt0 = kt * 64;
#pragma unroll
      for (int ni = 0; ni < 4; ++ni) {
        int key = kt0 + ni * 16 + l15;
#pragma unroll
        for (int r = 0; r < 4; ++r) {
          float arg = fmaf(sacc[ni][r], CSC, -B);
          float pv;
          if (diag) {
            int q = q0 + w * 16 + quad * 4 + r;
            pv = (key <= q) ? exp2f(arg) : 0.f;
          } else {
            pv = exp2f(arg);
          }
          Ps[w][quad * 4 + r][ni * 16 + l15] = f2bf(pv);
        }
      }

      // O += P V  (ni=8 tile: ones column -> row-sums accumulate in col 0)
      const ushort* VsC = Vs[cur];
#pragma unroll
      for (int ks2 = 0; ks2 < 2; ++ks2) {
        bf16x8 pf = *(const bf16x8*)(&Ps[w][l15][ks2 * 32 + quad * 8]);
#pragma unroll
        for (int ni = 0; ni < 9; ++ni) {
          int row = ni * 16 + l15;
          int pch = (ks2 * 4 + quad) ^ (row & 7);
          bf16x8 vf = *(const bf16x8*)(VsC + row * 64 + pch * 8);
          oacc[ni] = __builtin_amdgcn_mfma_f32_16x16x32_bf16(
              pf, vf, oacc[ni], 0, 0, 0);
        }
      }
    }

    // epilogue: write bf16 partial O ([h][q][d]) and fp32 partial l
    ushort* Op = s ? Op1 : Op0;
#pragma unroll
    for (int ni = 0; ni < 8; ++ni) {
      int d = ni * 16 + l15;
#pragma unroll
      for (int r = 0; r < 4; ++r) {
        int q = q0 + w * 16 + quad * 4 + r;
        Op[((size_t)h * T_SEQ + q) * DH + d] = f2bf(oacc[ni][r]);
      }
    }
    if (l15 == 0) {   // lane quad*16 holds l for its 4 rows in oacc[8]
#pragma unroll
      for (int r = 0; r < 4; ++r) {
        int q = q0 + w * 16 + quad * 4 + r;
        lpart[(size_t)s * (NH * T_SEQ) + h * T_SEQ + q] = oacc[8][r];
      }
    }
  }
}

// ---------------- combine: O=(O0+O1)/(l0+l1) * sigmoid(gate) -> ob16 ------
__global__ __launch_bounds__(256) void combine_kernel(
    const ushort* __restrict__ Op0, const ushort* __restrict__ Op1,
    const float* __restrict__ lpart, const ushort* __restrict__ qg16,
    ushort* __restrict__ ob16) {
  const int t = blockIdx.x, tid = threadIdx.x;
  const int h = tid >> 4, d0 = (tid & 15) * 8;
  const float l = lpart[h * T_SEQ + t] + lpart[NH * T_SEQ + h * T_SEQ + t];
  const float inv = 1.0f / l;
  const size_t po = ((size_t)h * T_SEQ + t) * DH + d0;
  ushort4 a0 = *(const ushort4*)(Op0 + po);
  ushort4 a1 = *(const ushort4*)(Op0 + po + 4);
  ushort4 b0 = *(const ushort4*)(Op1 + po);
  ushort4 b1 = *(const ushort4*)(Op1 + po + 4);
  const ushort* gp = qg16 + ((size_t)t * NH + h) * (2 * DH) + DH + d0;
  ushort4 g0 = *(const ushort4*)(gp);
  ushort4 g1 = *(const ushort4*)(gp + 4);
  float oa[8] = {bf2f(a0.x), bf2f(a0.y), bf2f(a0.z), bf2f(a0.w),
                 bf2f(a1.x), bf2f(a1.y), bf2f(a1.z), bf2f(a1.w)};
  float ob[8] = {bf2f(b0.x), bf2f(b0.y), bf2f(b0.z), bf2f(b0.w),
                 bf2f(b1.x), bf2f(b1.y), bf2f(b1.z), bf2f(b1.w)};
  float gg[8] = {bf2f(g0.x), bf2f(g0.y), bf2f(g0.z), bf2f(g0.w),
                 bf2f(g1.x), bf2f(g1.y), bf2f(g1.z), bf2f(g1.w)};
  ushort r[8];
#pragma unroll
  for (int i = 0; i < 8; ++i) {
    float o = (oa[i] + ob[i]) * inv;
    o = o / (1.0f + exp2f(-gg[i] * 1.44269504088896f));
    r[i] = f2bf(o);
  }
  ushort* op = ob16 + (size_t)t * (NH * DH) + h * DH + d0;
  *(ushort4*)(op)     = (ushort4){r[0], r[1], r[2], r[3]};
  *(ushort4*)(op + 4) = (ushort4){r[4], r[5], r[6], r[7]};
}

extern "C" void kernel_launch(void* const* d_in, const int* in_sizes, int n_in,
                              void* d_out, int out_size, void* d_ws, size_t ws_size,
                              hipStream_t stream) {
  const int*   positions = (const int*)d_in[0];
  const float* hs  = (const float*)d_in[1];
  const float* Wq  = (const float*)d_in[2];
  const float* Wk  = (const float*)d_in[3];
  const float* Wv  = (const float*)d_in[4];
  const float* Wo  = (const float*)d_in[5];
  const float* qnw = (const float*)d_in[6];
  const float* knw = (const float*)d_in[7];
  float* out = (float*)d_out;

  // workspace layout (64 MB), regions reused across pipeline stages:
  // [0,16)  qg16            (gemm_qkv -> combine, gate)
  // [16,24) Op0   bf16      (attn -> combine)   [over dead kb16/hs16]
  // [24,24.25) lpart fp32   (attn -> combine)   [over dead hs16]
  // [16,20) kb16            (gemm_qkv -> norm_rope)
  // [20,28) hs16            (prep -> gemm_qkv)
  // [28,44) Wqt             (prep -> gemm_qkv)
  // [28,36) q16             (norm_rope -> attn) [over dead Wqt]
  // [36,44) Wot             (prep_wo -> gemm_out) [over dead Wqt]
  // [44,48) Wkt -> k16      (norm_rope -> attn)
  // [48,52) Wvt ; [52,56) v16t (gemm_qkv -> attn)
  // [48,56) ob16            (combine -> gemm_out) [over dead Wvt/v16t]
  // [56,64) Op1   bf16      (attn -> combine)
  const size_t MB = 1 << 20;
  uint8_t* ws = (uint8_t*)d_ws;
  ushort* qg16 = (ushort*)(ws + 0);
  ushort* Op0  = (ushort*)(ws + 16 * MB);
  ushort* kb16 = (ushort*)(ws + 16 * MB);
  ushort* hs16 = (ushort*)(ws + 20 * MB);
  float*  lpart= (float*)(ws + 24 * MB);
  ushort* Wqt  = (ushort*)(ws + 28 * MB);
  ushort* q16  = (ushort*)(ws + 28 * MB);
  ushort* Wot  = (ushort*)(ws + 36 * MB);
  ushort* Wkt  = (ushort*)(ws + 44 * MB);
  ushort* k16  = (ushort*)(ws + 44 * MB);
  ushort* Wvt  = (ushort*)(ws + 48 * MB);
  ushort* ob16 = (ushort*)(ws + 48 * MB);
  ushort* v16t = (ushort*)(ws + 52 * MB);
  ushort* Op1  = (ushort*)(ws + 56 * MB);

  prep_kernel<<<16384, 256, 0, stream>>>(hs, Wq, Wk, Wv, hs16, Wqt, Wkt, Wvt);
  gemm_qkv<<<768, 256, 0, stream>>>(hs16, Wqt, Wkt, Wvt, qg16, kb16, v16t);
  norm_rope<<<dim3(T_SEQ, NH + NKV), 128, 0, stream>>>(qg16, kb16, positions,
                                                       qnw, knw, q16, k16);
  prep_wo<<<4096, 256, 0, stream>>>(Wo, Wot);
  attn_mfma<<<dim3(16, NH, 2), 256, 0, stream>>>(q16, k16, v16t, qnw, knw,
                                                 Op0, Op1, lpart);
  combine_kernel<<<T_SEQ, 256, 0, stream>>>(Op0, Op1, lpart, qg16, ob16);
  gemm_out<<<256, 256, 0, stream>>>(ob16, Wot, out);
}

// Round 5
// 297.538 us; speedup vs baseline: 6.7672x; 1.0131x over previous
//
#include <hip/hip_runtime.h>
#include <stdint.h>
#include <math.h>

// Problem constants
#define T_SEQ 2048
#define HID   2048
#define NH    16
#define NKV   8
#define DH    128

typedef __bf16 bf16x8 __attribute__((ext_vector_type(8)));
typedef float  f32x4  __attribute__((ext_vector_type(4)));

__device__ __forceinline__ ushort f2bf(float f) {   // round-to-nearest-even
  uint32_t u = __float_as_uint(f);
  u += 0x7FFF + ((u >> 16) & 1);
  return (ushort)(u >> 16);
}
__device__ __forceinline__ ushort f2bf_rz(float f) {  // truncate (for Ps; bias cancels in o/l)
  return (ushort)(__float_as_uint(f) >> 16);
}
__device__ __forceinline__ float bf2f(ushort u) {
  return __uint_as_float(((uint32_t)u) << 16);
}
// async global->LDS, 16B per lane; LDS dest = wave-uniform base + lane*16
__device__ __forceinline__ void gld16(const void* g, void* l) {
  __builtin_amdgcn_global_load_lds(
      (const __attribute__((address_space(1))) uint32_t*)g,
      (__attribute__((address_space(3))) uint32_t*)l, 16, 0, 0);
}

// ---------------- prep: hs conv + all W transposes (incl Wo) --------------
// flat grid: [0,4096) conv hs; [4096,12288) Wq^T; [12288,14336) Wk^T;
// [14336,16384) Wv^T; [16384,20480) Wo^T.
__global__ __launch_bounds__(256) void prep_kernel(
    const float* __restrict__ hs, const float* __restrict__ Wq,
    const float* __restrict__ Wk, const float* __restrict__ Wv,
    const float* __restrict__ Wo, ushort* __restrict__ hs16,
    ushort* __restrict__ Wqt, ushort* __restrict__ Wkt,
    ushort* __restrict__ Wvt, ushort* __restrict__ Wot) {
  __shared__ float tile[32][33];
  int bid = blockIdx.x;
  if (bid < 4096) {  // conv hs -> bf16
    int i = (bid * 256 + threadIdx.x) * 4;
    float4 v = *(const float4*)(hs + i);
    ushort4 o = {f2bf(v.x), f2bf(v.y), f2bf(v.z), f2bf(v.w)};
    *(ushort4*)(hs16 + i) = o;
    return;
  }
  bid -= 4096;
  const float* src; ushort* dst; int N, bi, bj;
  if (bid < 8192)       { src = Wq; dst = Wqt; N = 4096; bj = bid & 127; bi = bid >> 7; }
  else if (bid < 10240) { bid -= 8192;  src = Wk; dst = Wkt; N = 1024; bj = bid & 31; bi = bid >> 5; }
  else if (bid < 12288) { bid -= 10240; src = Wv; dst = Wvt; N = 1024; bj = bid & 31; bi = bid >> 5; }
  else                  { bid -= 12288; src = Wo; dst = Wot; N = 2048; bj = bid & 63; bi = bid >> 6; }
  int row = threadIdx.x >> 3, c4 = (threadIdx.x & 7) * 4;
  float4 v = *(const float4*)(src + (size_t)(bi * 32 + row) * N + bj * 32 + c4);
  tile[row][c4 + 0] = v.x; tile[row][c4 + 1] = v.y;
  tile[row][c4 + 2] = v.z; tile[row][c4 + 3] = v.w;
  __syncthreads();
  ushort4 o = {f2bf(tile[c4 + 0][row]), f2bf(tile[c4 + 1][row]),
               f2bf(tile[c4 + 2][row]), f2bf(tile[c4 + 3][row])};
  *(ushort4*)(dst + (size_t)(bj * 32 + row) * HID + bi * 32 + c4) = o;
}

// ---------------- bf16 MFMA GEMM K-loop: acc += A[m0:,:] @ Bt[n0:,:]^T ----
// MI = m-frags per wave (4 -> 128-row tile, 2 -> 64-row tile). N-tile = 128.
template <int MI>
__device__ __forceinline__ void gemm_loop(
    const ushort* __restrict__ A, const ushort* __restrict__ Bt,
    int K, int m0, int n0, ushort* As, ushort* Bs, f32x4 (*acc)[4]) {
  const int tid = threadIdx.x, lane = tid & 63, w = tid >> 6;
  const int quad = lane >> 4, l15 = lane & 15;
  const int wm = (w >> 1) * (MI * 16), wn = (w & 1) * 64;
  const int srow = tid >> 2, sch = tid & 3;
  for (int k0 = 0; k0 < K; k0 += 32) {
    __syncthreads();
#pragma unroll
    for (int p = 0; p < MI / 2; ++p) {
      int row = p * 64 + srow;
      int gch = sch ^ ((row >> 1) & 3);
      gld16(A + (size_t)(m0 + row) * K + k0 + gch * 8,
            As + (p * 256 + w * 64) * 8);
    }
#pragma unroll
    for (int p = 0; p < 2; ++p) {
      int row = p * 64 + srow;
      int gch = sch ^ ((row >> 1) & 3);
      gld16(Bt + (size_t)(n0 + row) * K + k0 + gch * 8,
            Bs + (p * 256 + w * 64) * 8);
    }
    __syncthreads();
    bf16x8 af[MI], bfr[4];
#pragma unroll
    for (int mi = 0; mi < MI; ++mi) {
      int row = wm + mi * 16 + l15;
      int pch = quad ^ ((row >> 1) & 3);
      af[mi] = *(const bf16x8*)(As + row * 32 + pch * 8);
    }
#pragma unroll
    for (int ni = 0; ni < 4; ++ni) {
      int row = wn + ni * 16 + l15;
      int pch = quad ^ ((row >> 1) & 3);
      bfr[ni] = *(const bf16x8*)(Bs + row * 32 + pch * 8);
    }
#pragma unroll
    for (int mi = 0; mi < MI; ++mi)
#pragma unroll
      for (int ni = 0; ni < 4; ++ni)
        acc[mi][ni] = __builtin_amdgcn_mfma_f32_16x16x32_bf16(
            af[mi], bfr[ni], acc[mi][ni], 0, 0, 0);
  }
}

// generic bf16 tile store (C/D layout: col = l15, row = quad*4 + reg)
__device__ __forceinline__ void bf16_store(f32x4 (*acc)[4],
                                           ushort* __restrict__ Cb, int Ncols,
                                           int m0, int n0) {
  const int lane = threadIdx.x & 63, w = threadIdx.x >> 6;
  const int quad = lane >> 4, l15 = lane & 15;
  const int wm = (w >> 1) * 64, wn = (w & 1) * 64;
#pragma unroll
  for (int mi = 0; mi < 4; ++mi)
#pragma unroll
    for (int ni = 0; ni < 4; ++ni)
#pragma unroll
      for (int r = 0; r < 4; ++r) {
        int row = m0 + wm + mi * 16 + quad * 4 + r;
        int col = n0 + wn + ni * 16 + l15;
        Cb[(size_t)row * Ncols + col] = f2bf(acc[mi][ni][r]);
      }
}

// Fused RMSNorm + RoPE epilogue for a 128x128 tile whose columns are one
// head's 128 dims. Reuses staging LDS (barrier-protected) for the bf16
// tile; row sums via l15-shuffle + cross-wave LDS combine.
__device__ __forceinline__ void norm_rope_epilogue(
    f32x4 (*acc)[4], const float* __restrict__ wgt,
    const int* __restrict__ positions, int m0, ushort* __restrict__ outp,
    int ostride, char* smem) {
  ushort* tile = (ushort*)smem;            // 128 x 136 bf16
  float* ssum = (float*)(smem + 34816);    // [2][128]
  const int tid = threadIdx.x, lane = tid & 63, w = tid >> 6;
  const int quad = lane >> 4, l15 = lane & 15;
  const int wm = (w >> 1) * 64, wn = (w & 1) * 64;
  float sp[4][4];
#pragma unroll
  for (int mi = 0; mi < 4; ++mi)
#pragma unroll
    for (int r = 0; r < 4; ++r) {
      float s = 0.f;
#pragma unroll
      for (int ni = 0; ni < 4; ++ni) { float v = acc[mi][ni][r]; s += v * v; }
#pragma unroll
      for (int off = 1; off <= 8; off <<= 1) s += __shfl_xor(s, off, 64);
      sp[mi][r] = s;
    }
  if (l15 == 0) {
#pragma unroll
    for (int mi = 0; mi < 4; ++mi)
#pragma unroll
      for (int r = 0; r < 4; ++r)
        ssum[(w & 1) * 128 + wm + mi * 16 + quad * 4 + r] = sp[mi][r];
  }
  __syncthreads();   // ssum visible AND all waves done reading As/Bs
  float wv[4];
#pragma unroll
  for (int ni = 0; ni < 4; ++ni) wv[ni] = 1.f + wgt[wn + ni * 16 + l15];
#pragma unroll
  for (int mi = 0; mi < 4; ++mi)
#pragma unroll
    for (int r = 0; r < 4; ++r) {
      int row = wm + mi * 16 + quad * 4 + r;
      float inv = rsqrtf((ssum[row] + ssum[128 + row]) * (1.f / 128.f) + 1e-6f);
#pragma unroll
      for (int ni = 0; ni < 4; ++ni)
        tile[row * 136 + wn + ni * 16 + l15] =
            f2bf(acc[mi][ni][r] * inv * wv[ni]);
    }
  __syncthreads();
  // RoPE: 2 threads per row; d in [d0, d0+32). sin/cos in revolution
  // domain via v_fract reduction (angle err ~1e-4, << bf16 grain).
  const int row = tid >> 1, d0 = (tid & 1) * 32;
  const float pos = (float)positions[m0 + row];
  __align__(16) ushort lo[32], hi[32];
#pragma unroll
  for (int j = 0; j < 32; ++j) {
    int d = d0 + j;
    // inv_freq/(2pi) = 2^(-d*log2(10000)/64) * 0.15915494
    float rev = pos * exp2f((float)d * -0.20762050593045233f) *
                0.15915494309189535f;
    float fr = rev - floorf(rev);
    float s = __builtin_amdgcn_sinf(fr);
    float c = __builtin_amdgcn_cosf(fr);
    float x1 = bf2f(tile[row * 136 + d]);
    float x2 = bf2f(tile[row * 136 + d + 64]);
    lo[j] = f2bf(x1 * c - x2 * s);
    hi[j] = f2bf(x2 * c + x1 * s);
  }
  ushort* op = outp + (size_t)(m0 + row) * ostride + d0;
#pragma unroll
  for (int j = 0; j < 4; ++j) {
    *((uint4*)op + j)        = ((const uint4*)lo)[j];
    *((uint4*)(op + 64) + j) = ((const uint4*)hi)[j];
  }
}

// Fused QKV projections + q/k RMSNorm+RoPE + gate extraction.
// [0,512): Q/gate; [512,640): K; [640,768): V^T = Wvt @ hs16^T.
__global__ __launch_bounds__(256) void gemm_qkv(
    const ushort* __restrict__ hs16, const ushort* __restrict__ Wqt,
    const ushort* __restrict__ Wkt, const ushort* __restrict__ Wvt,
    const int* __restrict__ positions, const float* __restrict__ qnw,
    const float* __restrict__ knw, ushort* __restrict__ q16,
    ushort* __restrict__ gate16, ushort* __restrict__ k16,
    ushort* __restrict__ v16t) {
  __shared__ __align__(16) char smem[35840 + 1024];  // staging 16KB | tile+ssum
  ushort* As = (ushort*)smem;
  ushort* Bs = As + 4096;
  f32x4 acc[4][4];
#pragma unroll
  for (int i = 0; i < 4; ++i)
#pragma unroll
    for (int j = 0; j < 4; ++j) acc[i][j] = (f32x4){0.f, 0.f, 0.f, 0.f};
  const int b = blockIdx.x;
  if (b < 512) {
    int mt = b >> 5, nt = b & 31, m0 = mt * 128, h = nt >> 1;
    gemm_loop<4>(hs16, Wqt, HID, m0, nt * 128, As, Bs, acc);
    if ((nt & 1) == 0)
      norm_rope_epilogue(acc, qnw, positions, m0, q16 + h * DH, NH * DH, smem);
    else
      bf16_store(acc, gate16, NH * DH, m0, h * DH);
  } else if (b < 640) {
    int f = b - 512, mt = f >> 3, nt = f & 7, m0 = mt * 128;
    gemm_loop<4>(hs16, Wkt, HID, m0, nt * 128, As, Bs, acc);
    norm_rope_epilogue(acc, knw, positions, m0, k16 + nt * DH, NKV * DH, smem);
  } else {
    int f = b - 640, mt = f >> 4, nt = f & 15;
    gemm_loop<4>(Wvt, hs16, HID, mt * 128, nt * 128, As, Bs, acc);
    bf16_store(acc, v16t, T_SEQ, mt * 128, nt * 128);
  }
}

// Output projection: 64x128 tiles (512 blocks = 2/CU for latency hiding).
__global__ __launch_bounds__(256) void gemm_out(
    const ushort* __restrict__ ob16, const ushort* __restrict__ Wot,
    float* __restrict__ out) {
  __shared__ ushort As[64 * 32];
  __shared__ ushort Bs[128 * 32];
  f32x4 acc[2][4];
#pragma unroll
  for (int i = 0; i < 2; ++i)
#pragma unroll
    for (int j = 0; j < 4; ++j) acc[i][j] = (f32x4){0.f, 0.f, 0.f, 0.f};
  const int b = blockIdx.x;
  const int m0 = (b >> 4) * 64, n0 = (b & 15) * 128;
  gemm_loop<2>(ob16, Wot, HID, m0, n0, As, Bs, acc);
  const int lane = threadIdx.x & 63, w = threadIdx.x >> 6;
  const int quad = lane >> 4, l15 = lane & 15;
  const int wm = (w >> 1) * 32, wn = (w & 1) * 64;
#pragma unroll
  for (int mi = 0; mi < 2; ++mi)
#pragma unroll
    for (int ni = 0; ni < 4; ++ni)
#pragma unroll
      for (int r = 0; r < 4; ++r) {
        int row = m0 + wm + mi * 16 + quad * 4 + r;
        int col = n0 + wn + ni * 16 + l15;
        out[(size_t)row * HID + col] = acc[mi][ni][r];
      }
}

// ---------------- MFMA flash attention, key-split x2 ----------------------
// grid (16, NH, 2): block (pb,h,s) processes q-tiles {pb, 31-pb}, k-tiles
// kt ≡ s (mod 2). Static softmax bound B -> partials summable across splits.
__global__ __launch_bounds__(256) void attn_mfma(
    const ushort* __restrict__ q16, const ushort* __restrict__ k16,
    const ushort* __restrict__ v16t, const float* __restrict__ qnw,
    const float* __restrict__ knw, ushort* __restrict__ Op0,
    ushort* __restrict__ Op1, float* __restrict__ lpart) {
  const int pb = blockIdx.x, h = blockIdx.y, s = blockIdx.z, kvh = h >> 1;
  const int tid = threadIdx.x, lane = tid & 63, w = tid >> 6;
  const int quad = lane >> 4, l15 = lane & 15;

  __shared__ ushort Ks[2][64 * 128];
  __shared__ ushort Vs[2][144 * 64];   // rows 128..143: ones row + zeros
  __shared__ ushort Ps[4][16][72];

  // init constant rows of Vs (row 128 = 1.0, 129..143 = 0); staging only
  // writes rows 0..127, so this survives all iterations.
#pragma unroll
  for (int buf = 0; buf < 2; ++buf)
    for (int i = tid; i < 16 * 64; i += 256) {
      int row = 128 + (i >> 6), col = i & 63;
      Vs[buf][row * 64 + col] = (row == 128) ? (ushort)0x3F80 : (ushort)0;
    }

  // score bound B (log2 domain), computed redundantly per block (cheap)
  __shared__ float s8[8];
  __shared__ float bshare;
  {
    float mq = 0.f, mk = 0.f;
    if (tid < 128) { mq = fabsf(1.f + qnw[tid]); mk = fabsf(1.f + knw[tid]); }
#pragma unroll
    for (int off = 32; off >= 1; off >>= 1) {
      mq = fmaxf(mq, __shfl_xor(mq, off, 64));
      mk = fmaxf(mk, __shfl_xor(mk, off, 64));
    }
    if (lane == 0) { s8[w * 2] = mq; s8[w * 2 + 1] = mk; }
    __syncthreads();
    if (tid == 0) {
      float MQ = fmaxf(s8[0], s8[2]), MK = fmaxf(s8[1], s8[3]);
      // sqrt(128)*log2(e) = 16.3217; 2% + 0.1 safety margin
      bshare = 16.3217f * MQ * MK * 1.02f + 0.1f;
    }
    __syncthreads();
  }
  const float B = bshare;
  const float CSC = 0.08838834764831845f * 1.44269504088896f;  // scale*log2e

#pragma unroll 1
  for (int sel = 0; sel < 2; ++sel) {
    const int qt = sel ? (31 - pb) : pb;
    const int q0 = qt * 64, nk = qt + 1;
    const int ntl = (nk > s) ? ((nk - s + 1) >> 1) : 0;  // tiles s, s+2, ...

    bf16x8 qf[4];
    const ushort* qbase = q16 + ((size_t)(q0 + w * 16 + l15) * NH + h) * DH;
#pragma unroll
    for (int ks = 0; ks < 4; ++ks)
      qf[ks] = *(const bf16x8*)(qbase + ks * 32 + quad * 8);

    f32x4 oacc[9];
#pragma unroll
    for (int i = 0; i < 9; ++i) oacc[i] = (f32x4){0.f, 0.f, 0.f, 0.f};

    __syncthreads();  // prior q-tile's buffer readers done before restage
    if (ntl > 0) {    // stage first tile (kt = s) into buf 0
      const int kt0 = s * 64;
#pragma unroll
      for (int p = 0; p < 4; ++p) {
        int row = p * 16 + (tid >> 4), ch = tid & 15;
        int gch = ch ^ (row & 15);
        gld16(k16 + ((size_t)(kt0 + row) * NKV + kvh) * DH + gch * 8,
              (ushort*)Ks[0] + (p * 256 + w * 64) * 8);
      }
#pragma unroll
      for (int p = 0; p < 4; ++p) {
        int row = p * 32 + (tid >> 3), ch = tid & 7;
        int gch = ch ^ (row & 7);
        gld16(v16t + (size_t)(kvh * DH + row) * T_SEQ + kt0 + gch * 8,
              (ushort*)Vs[0] + (p * 256 + w * 64) * 8);
      }
    }

#pragma unroll 1
    for (int it = 0; it < ntl; ++it) {
      const int kt = s + 2 * it;
      const int cur = it & 1;
      __syncthreads();  // staged buf[cur] landed; prior reads of buf[!cur] done
      if (it + 1 < ntl) {  // prefetch tile kt+2; flies during compute below
        const int nt0 = (kt + 2) * 64;
#pragma unroll
        for (int p = 0; p < 4; ++p) {
          int row = p * 16 + (tid >> 4), ch = tid & 15;
          int gch = ch ^ (row & 15);
          gld16(k16 + ((size_t)(nt0 + row) * NKV + kvh) * DH + gch * 8,
                (ushort*)Ks[1 - cur] + (p * 256 + w * 64) * 8);
        }
#pragma unroll
        for (int p = 0; p < 4; ++p) {
          int row = p * 32 + (tid >> 3), ch = tid & 7;
          int gch = ch ^ (row & 7);
          gld16(v16t + (size_t)(kvh * DH + row) * T_SEQ + nt0 + gch * 8,
                (ushort*)Vs[1 - cur] + (p * 256 + w * 64) * 8);
        }
      }

      // S = Q K^T
      f32x4 sacc[4];
#pragma unroll
      for (int ni = 0; ni < 4; ++ni) sacc[ni] = (f32x4){0.f, 0.f, 0.f, 0.f};
      const ushort* KsC = Ks[cur];
#pragma unroll
      for (int ks = 0; ks < 4; ++ks)
#pragma unroll
        for (int ni = 0; ni < 4; ++ni) {
          int row = ni * 16 + l15;
          int pch = (ks * 4 + quad) ^ (row & 15);
          bf16x8 kf = *(const bf16x8*)(KsC + row * 128 + pch * 8);
          sacc[ni] = __builtin_amdgcn_mfma_f32_16x16x32_bf16(
              qf[ks], kf, sacc[ni], 0, 0, 0);
        }

      // p = exp2(s*CSC - B); mask only on the diagonal tile
      const bool diag = (kt == qt);
      const int kt0 = kt * 64;
#pragma unroll
      for (int ni = 0; ni < 4; ++ni) {
        int key = kt0 + ni * 16 + l15;
#pragma unroll
        for (int r = 0; r < 4; ++r) {
          float arg = fmaf(sacc[ni][r], CSC, -B);
          float pv;
          if (diag) {
            int q = q0 + w * 16 + quad * 4 + r;
            pv = (key <= q) ? exp2f(arg) : 0.f;
          } else {
            pv = exp2f(arg);
          }
          Ps[w][quad * 4 + r][ni * 16 + l15] = f2bf_rz(pv);
        }
      }

      // O += P V  (ni=8 tile: ones column -> row-sums accumulate in col 0)
      const ushort* VsC = Vs[cur];
#pragma unroll
      for (int ks2 = 0; ks2 < 2; ++ks2) {
        bf16x8 pf = *(const bf16x8*)(&Ps[w][l15][ks2 * 32 + quad * 8]);
#pragma unroll
        for (int ni = 0; ni < 9; ++ni) {
          int row = ni * 16 + l15;
          int pch = (ks2 * 4 + quad) ^ (row & 7);
          bf16x8 vf = *(const bf16x8*)(VsC + row * 64 + pch * 8);
          oacc[ni] = __builtin_amdgcn_mfma_f32_16x16x32_bf16(
              pf, vf, oacc[ni], 0, 0, 0);
        }
      }
    }

    // epilogue: write bf16 partial O ([h][q][d]) and fp32 partial l
    ushort* Op = s ? Op1 : Op0;
#pragma unroll
    for (int ni = 0; ni < 8; ++ni) {
      int d = ni * 16 + l15;
#pragma unroll
      for (int r = 0; r < 4; ++r) {
        int q = q0 + w * 16 + quad * 4 + r;
        Op[((size_t)h * T_SEQ + q) * DH + d] = f2bf(oacc[ni][r]);
      }
    }
    if (l15 == 0) {   // lane quad*16 holds l for its 4 rows in oacc[8]
#pragma unroll
      for (int r = 0; r < 4; ++r) {
        int q = q0 + w * 16 + quad * 4 + r;
        lpart[(size_t)s * (NH * T_SEQ) + h * T_SEQ + q] = oacc[8][r];
      }
    }
  }
}

// ---------------- combine: O=(O0+O1)/(l0+l1) * sigmoid(gate) -> ob16 ------
__global__ __launch_bounds__(256) void combine_kernel(
    const ushort* __restrict__ Op0, const ushort* __restrict__ Op1,
    const float* __restrict__ lpart, const ushort* __restrict__ gate16,
    ushort* __restrict__ ob16) {
  const int t = blockIdx.x, tid = threadIdx.x;
  const int h = tid >> 4, d0 = (tid & 15) * 8;
  const float l = lpart[h * T_SEQ + t] + lpart[NH * T_SEQ + h * T_SEQ + t];
  const float inv = 1.0f / l;
  const size_t po = ((size_t)h * T_SEQ + t) * DH + d0;
  ushort4 a0 = *(const ushort4*)(Op0 + po);
  ushort4 a1 = *(const ushort4*)(Op0 + po + 4);
  ushort4 b0 = *(const ushort4*)(Op1 + po);
  ushort4 b1 = *(const ushort4*)(Op1 + po + 4);
  const ushort* gp = gate16 + (size_t)t * (NH * DH) + h * DH + d0;
  ushort4 g0 = *(const ushort4*)(gp);
  ushort4 g1 = *(const ushort4*)(gp + 4);
  float oa[8] = {bf2f(a0.x), bf2f(a0.y), bf2f(a0.z), bf2f(a0.w),
                 bf2f(a1.x), bf2f(a1.y), bf2f(a1.z), bf2f(a1.w)};
  float ob[8] = {bf2f(b0.x), bf2f(b0.y), bf2f(b0.z), bf2f(b0.w),
                 bf2f(b1.x), bf2f(b1.y), bf2f(b1.z), bf2f(b1.w)};
  float gg[8] = {bf2f(g0.x), bf2f(g0.y), bf2f(g0.z), bf2f(g0.w),
                 bf2f(g1.x), bf2f(g1.y), bf2f(g1.z), bf2f(g1.w)};
  ushort r[8];
#pragma unroll
  for (int i = 0; i < 8; ++i) {
    float o = (oa[i] + ob[i]) * inv;
    o = o / (1.0f + exp2f(-gg[i] * 1.44269504088896f));
    r[i] = f2bf(o);
  }
  ushort* op = ob16 + (size_t)t * (NH * DH) + h * DH + d0;
  *(ushort4*)(op)     = (ushort4){r[0], r[1], r[2], r[3]};
  *(ushort4*)(op + 4) = (ushort4){r[4], r[5], r[6], r[7]};
}

extern "C" void kernel_launch(void* const* d_in, const int* in_sizes, int n_in,
                              void* d_out, int out_size, void* d_ws, size_t ws_size,
                              hipStream_t stream) {
  const int*   positions = (const int*)d_in[0];
  const float* hs  = (const float*)d_in[1];
  const float* Wq  = (const float*)d_in[2];
  const float* Wk  = (const float*)d_in[3];
  const float* Wv  = (const float*)d_in[4];
  const float* Wo  = (const float*)d_in[5];
  const float* qnw = (const float*)d_in[6];
  const float* knw = (const float*)d_in[7];
  float* out = (float*)d_out;

  // workspace layout (64 MB), region reuse:
  // [0,8)   hs16 (prep->qkv)        -> Op0   (attn->combine)
  // [8,24)  Wqt  (prep->qkv)        -> Op1 [8,16) ; ob16 [16,24)
  // [24,28) Wkt  (prep->qkv)        -> lpart [24,24.25)
  // [28,32) Wvt  (prep->qkv)
  // [32,40) gate16 (qkv->combine)
  // [40,48) q16  (qkv->attn)
  // [48,52) k16  (qkv->attn)
  // [52,56) v16t (qkv->attn)
  // [56,64) Wot  (prep->gemm_out)
  const size_t MB = 1 << 20;
  uint8_t* ws = (uint8_t*)d_ws;
  ushort* hs16  = (ushort*)(ws + 0);
  ushort* Op0   = (ushort*)(ws + 0);
  ushort* Wqt   = (ushort*)(ws + 8 * MB);
  ushort* Op1   = (ushort*)(ws + 8 * MB);
  ushort* ob16  = (ushort*)(ws + 16 * MB);
  ushort* Wkt   = (ushort*)(ws + 24 * MB);
  float*  lpart = (float*)(ws + 24 * MB);
  ushort* Wvt   = (ushort*)(ws + 28 * MB);
  ushort* gate16= (ushort*)(ws + 32 * MB);
  ushort* q16   = (ushort*)(ws + 40 * MB);
  ushort* k16   = (ushort*)(ws + 48 * MB);
  ushort* v16t  = (ushort*)(ws + 52 * MB);
  ushort* Wot   = (ushort*)(ws + 56 * MB);

  prep_kernel<<<20480, 256, 0, stream>>>(hs, Wq, Wk, Wv, Wo,
                                         hs16, Wqt, Wkt, Wvt, Wot);
  gemm_qkv<<<768, 256, 0, stream>>>(hs16, Wqt, Wkt, Wvt, positions, qnw, knw,
                                    q16, gate16, k16, v16t);
  attn_mfma<<<dim3(16, NH, 2), 256, 0, stream>>>(q16, k16, v16t, qnw, knw,
                                                 Op0, Op1, lpart);
  combine_kernel<<<T_SEQ, 256, 0, stream>>>(Op0, Op1, lpart, gate16, ob16);
  gemm_out<<<512, 256, 0, stream>>>(ob16, Wot, out);
}

// Round 6
// 289.475 us; speedup vs baseline: 6.9557x; 1.0279x over previous
//
#include <hip/hip_runtime.h>
#include <stdint.h>
#include <math.h>

// Problem constants
#define T_SEQ 2048
#define HID   2048
#define NH    16
#define NKV   8
#define DH    128

typedef __bf16 bf16x8 __attribute__((ext_vector_type(8)));
typedef float  f32x4  __attribute__((ext_vector_type(4)));

__device__ __forceinline__ ushort f2bf(float f) {   // round-to-nearest-even
  uint32_t u = __float_as_uint(f);
  u += 0x7FFF + ((u >> 16) & 1);
  return (ushort)(u >> 16);
}
__device__ __forceinline__ ushort f2bf_rz(float f) {  // truncate (Ps; bias cancels in o/l)
  return (ushort)(__float_as_uint(f) >> 16);
}
__device__ __forceinline__ float bf2f(ushort u) {
  return __uint_as_float(((uint32_t)u) << 16);
}
// async global->LDS, 16B per lane; LDS dest = wave-uniform base + lane*16
__device__ __forceinline__ void gld16(const void* g, void* l) {
  __builtin_amdgcn_global_load_lds(
      (const __attribute__((address_space(1))) uint32_t*)g,
      (__attribute__((address_space(3))) uint32_t*)l, 16, 0, 0);
}

// ---------------- prep: hs conv + all W transposes (64x64 tiles) ----------
// flat grid: [0,4096) conv hs; [4096,6144) Wq^T; [6144,6656) Wk^T;
// [6656,7168) Wv^T; [7168,8192) Wo^T.
__global__ __launch_bounds__(256) void prep_kernel(
    const float* __restrict__ hs, const float* __restrict__ Wq,
    const float* __restrict__ Wk, const float* __restrict__ Wv,
    const float* __restrict__ Wo, ushort* __restrict__ hs16,
    ushort* __restrict__ Wqt, ushort* __restrict__ Wkt,
    ushort* __restrict__ Wvt, ushort* __restrict__ Wot) {
  int bid = blockIdx.x;
  if (bid < 4096) {  // conv hs -> bf16
    int i = (bid * 256 + threadIdx.x) * 4;
    float4 v = *(const float4*)(hs + i);
    ushort4 o = {f2bf(v.x), f2bf(v.y), f2bf(v.z), f2bf(v.w)};
    *(ushort4*)(hs16 + i) = o;
    return;
  }
  bid -= 4096;
  const float* src; ushort* dst; int N, bi, bj;
  if (bid < 2048)      { src = Wq; dst = Wqt; N = 4096; bj = bid & 63; bi = bid >> 6; }
  else if (bid < 2560) { bid -= 2048; src = Wk; dst = Wkt; N = 1024; bj = bid & 15; bi = bid >> 4; }
  else if (bid < 3072) { bid -= 2560; src = Wv; dst = Wvt; N = 1024; bj = bid & 15; bi = bid >> 4; }
  else                 { bid -= 3072; src = Wo; dst = Wot; N = 2048; bj = bid & 31; bi = bid >> 5; }
  __shared__ float tile[64][65];
  const int r = threadIdx.x >> 2, cg = (threadIdx.x & 3) * 16;
  const float* sp = src + (size_t)(bi * 64 + r) * N + bj * 64 + cg;
#pragma unroll
  for (int p = 0; p < 4; ++p) {
    float4 v = *(const float4*)(sp + p * 4);
    tile[r][cg + p * 4 + 0] = v.x; tile[r][cg + p * 4 + 1] = v.y;
    tile[r][cg + p * 4 + 2] = v.z; tile[r][cg + p * 4 + 3] = v.w;
  }
  __syncthreads();
  ushort* dp = dst + (size_t)(bj * 64 + r) * HID + bi * 64 + cg;
#pragma unroll
  for (int p = 0; p < 2; ++p) {
    union { uint4 v; ushort u[8]; } o;
#pragma unroll
    for (int j = 0; j < 8; ++j) o.u[j] = f2bf(tile[cg + p * 8 + j][r]);
    *(uint4*)(dp + p * 8) = o.v;
  }
}

// ---------------- bf16 MFMA GEMM K-loop: acc += A[m0:,:] @ Bt[n0:,:]^T ----
// MI = m-frags per wave (4 -> 128-row tile, 2 -> 64-row tile). N-tile = 128.
template <int MI>
__device__ __forceinline__ void gemm_loop(
    const ushort* __restrict__ A, const ushort* __restrict__ Bt,
    int K, int m0, int n0, ushort* As, ushort* Bs, f32x4 (*acc)[4]) {
  const int tid = threadIdx.x, lane = tid & 63, w = tid >> 6;
  const int quad = lane >> 4, l15 = lane & 15;
  const int wm = (w >> 1) * (MI * 16), wn = (w & 1) * 64;
  const int srow = tid >> 2, sch = tid & 3;
  for (int k0 = 0; k0 < K; k0 += 32) {
    __syncthreads();
#pragma unroll
    for (int p = 0; p < MI / 2; ++p) {
      int row = p * 64 + srow;
      int gch = sch ^ ((row >> 1) & 3);
      gld16(A + (size_t)(m0 + row) * K + k0 + gch * 8,
            As + (p * 256 + w * 64) * 8);
    }
#pragma unroll
    for (int p = 0; p < 2; ++p) {
      int row = p * 64 + srow;
      int gch = sch ^ ((row >> 1) & 3);
      gld16(Bt + (size_t)(n0 + row) * K + k0 + gch * 8,
            Bs + (p * 256 + w * 64) * 8);
    }
    __syncthreads();
    bf16x8 af[MI], bfr[4];
#pragma unroll
    for (int mi = 0; mi < MI; ++mi) {
      int row = wm + mi * 16 + l15;
      int pch = quad ^ ((row >> 1) & 3);
      af[mi] = *(const bf16x8*)(As + row * 32 + pch * 8);
    }
#pragma unroll
    for (int ni = 0; ni < 4; ++ni) {
      int row = wn + ni * 16 + l15;
      int pch = quad ^ ((row >> 1) & 3);
      bfr[ni] = *(const bf16x8*)(Bs + row * 32 + pch * 8);
    }
#pragma unroll
    for (int mi = 0; mi < MI; ++mi)
#pragma unroll
      for (int ni = 0; ni < 4; ++ni)
        acc[mi][ni] = __builtin_amdgcn_mfma_f32_16x16x32_bf16(
            af[mi], bfr[ni], acc[mi][ni], 0, 0, 0);
  }
}

// bf16 tile store (C/D layout: col = l15, row = quad*4 + reg)
__device__ __forceinline__ void bf16_store(f32x4 (*acc)[4],
                                           ushort* __restrict__ Cb, int Ncols,
                                           int m0, int n0) {
  const int lane = threadIdx.x & 63, w = threadIdx.x >> 6;
  const int quad = lane >> 4, l15 = lane & 15;
  const int wm = (w >> 1) * 64, wn = (w & 1) * 64;
#pragma unroll
  for (int mi = 0; mi < 4; ++mi)
#pragma unroll
    for (int ni = 0; ni < 4; ++ni)
#pragma unroll
      for (int r = 0; r < 4; ++r) {
        int row = m0 + wm + mi * 16 + quad * 4 + r;
        int col = n0 + wn + ni * 16 + l15;
        Cb[(size_t)row * Ncols + col] = f2bf(acc[mi][ni][r]);
      }
}

// Fused QKV projections (lean r4 structure — no epilogue fusion).
// [0,512): Q/gate -> qg16; [512,640): K -> kb16; [640,768): V^T -> v16t.
__global__ __launch_bounds__(256) void gemm_qkv(
    const ushort* __restrict__ hs16, const ushort* __restrict__ Wqt,
    const ushort* __restrict__ Wkt, const ushort* __restrict__ Wvt,
    ushort* __restrict__ qg16, ushort* __restrict__ kb16,
    ushort* __restrict__ v16t) {
  __shared__ ushort As[128 * 32];
  __shared__ ushort Bs[128 * 32];
  f32x4 acc[4][4];
#pragma unroll
  for (int i = 0; i < 4; ++i)
#pragma unroll
    for (int j = 0; j < 4; ++j) acc[i][j] = (f32x4){0.f, 0.f, 0.f, 0.f};
  const int b = blockIdx.x;
  if (b < 512) {
    int m0 = (b >> 5) * 128, n0 = (b & 31) * 128;
    gemm_loop<4>(hs16, Wqt, HID, m0, n0, As, Bs, acc);
    bf16_store(acc, qg16, 4096, m0, n0);
  } else if (b < 640) {
    int f = b - 512, m0 = (f >> 3) * 128, n0 = (f & 7) * 128;
    gemm_loop<4>(hs16, Wkt, HID, m0, n0, As, Bs, acc);
    bf16_store(acc, kb16, 1024, m0, n0);
  } else {
    int f = b - 640, m0 = (f >> 4) * 128, n0 = (f & 15) * 128;
    gemm_loop<4>(Wvt, hs16, HID, m0, n0, As, Bs, acc);
    bf16_store(acc, v16t, T_SEQ, m0, n0);
  }
}

// Output projection: 64x128 tiles (512 blocks = 2/CU).
__global__ __launch_bounds__(256) void gemm_out(
    const ushort* __restrict__ ob16, const ushort* __restrict__ Wot,
    float* __restrict__ out) {
  __shared__ ushort As[64 * 32];
  __shared__ ushort Bs[128 * 32];
  f32x4 acc[2][4];
#pragma unroll
  for (int i = 0; i < 2; ++i)
#pragma unroll
    for (int j = 0; j < 4; ++j) acc[i][j] = (f32x4){0.f, 0.f, 0.f, 0.f};
  const int b = blockIdx.x;
  const int m0 = (b >> 4) * 64, n0 = (b & 15) * 128;
  gemm_loop<2>(ob16, Wot, HID, m0, n0, As, Bs, acc);
  const int lane = threadIdx.x & 63, w = threadIdx.x >> 6;
  const int quad = lane >> 4, l15 = lane & 15;
  const int wm = (w >> 1) * 32, wn = (w & 1) * 64;
#pragma unroll
  for (int mi = 0; mi < 2; ++mi)
#pragma unroll
    for (int ni = 0; ni < 4; ++ni)
#pragma unroll
      for (int r = 0; r < 4; ++r) {
        int row = m0 + wm + mi * 16 + quad * 4 + r;
        int col = n0 + wn + ni * 16 + l15;
        out[(size_t)row * HID + col] = acc[mi][ni][r];
      }
}

// ---------------- RMSNorm + RoPE for K only (q fused into attn) -----------
__global__ __launch_bounds__(128) void norm_k(
    const ushort* __restrict__ kb16, const int* __restrict__ positions,
    const float* __restrict__ kw, ushort* __restrict__ k16) {
  const int t = blockIdx.x, kv = blockIdx.y, d = threadIdx.x;
  const ushort* x = kb16 + ((size_t)t * NKV + kv) * DH;
  ushort* out = k16 + ((size_t)t * NKV + kv) * DH;
  float v = bf2f(x[d]);
  float ss = v * v;
#pragma unroll
  for (int off = 32; off >= 1; off >>= 1) ss += __shfl_xor(ss, off, 64);
  __shared__ float red[2];
  if ((d & 63) == 0) red[d >> 6] = ss;
  __syncthreads();
  float mean = (red[0] + red[1]) * (1.0f / 128.0f);
  float xn = v * rsqrtf(mean + 1e-6f) * (1.0f + kw[d]);
  __shared__ float sh[128];
  sh[d] = xn;
  __syncthreads();
  if (d < 64) {
    float pos = (float)positions[t];
    // angle in revolutions: pos * 10000^(-d/64) / (2*pi)
    float rev = pos * exp2f((float)d * -0.20762050593045233f) *
                0.15915494309189535f;
    float fr = rev - floorf(rev);
    float s = __builtin_amdgcn_sinf(fr);
    float c = __builtin_amdgcn_cosf(fr);
    float x1 = sh[d], x2 = sh[d + 64];
    out[d]      = f2bf(x1 * c - x2 * s);
    out[d + 64] = f2bf(x2 * c + x1 * s);
  }
}

// ---------------- MFMA flash attention, key-split x3, single-buffer -------
// grid (16, NH, 3): block (pb,h,s) does q-tiles {pb, 31-pb}, k-tiles
// kt ≡ s (mod 3). q-RMSNorm+RoPE fused in-register in the prologue
// (A-frag layout: row = l15, d = ks*32+quad*8+j; the RoPE pair (d,d+64)
// sits in the same lane at frags ks, ks+2). Static softmax bound B ->
// partials summable; combine_kernel merges the 3 splits.
__global__ __launch_bounds__(256) void attn_mfma(
    const ushort* __restrict__ qg16, const ushort* __restrict__ k16,
    const ushort* __restrict__ v16t, const int* __restrict__ positions,
    const float* __restrict__ qnw, const float* __restrict__ knw,
    ushort* __restrict__ Op0, ushort* __restrict__ Op1,
    ushort* __restrict__ Op2, float* __restrict__ lpart) {
  const int pb = blockIdx.x, h = blockIdx.y, s = blockIdx.z, kvh = h >> 1;
  const int tid = threadIdx.x, lane = tid & 63, w = tid >> 6;
  const int quad = lane >> 4, l15 = lane & 15;

  __shared__ ushort Ks[64 * 128];     // 16 KB
  __shared__ ushort Vs[144 * 64];     // 18 KB; rows 128..143 constant
  __shared__ ushort Ps[4][16][72];    // 9.2 KB, per-wave

  // constant rows of Vs: row 128 = 1.0 (row-sum via MFMA), 129..143 = 0
  for (int i = tid; i < 16 * 64; i += 256) {
    int row = 128 + (i >> 6), col = i & 63;
    Vs[row * 64 + col] = (row == 128) ? (ushort)0x3F80 : (ushort)0;
  }

  // score bound B (log2 domain)
  __shared__ float s8[8];
  __shared__ float bshare;
  {
    float mq = 0.f, mk = 0.f;
    if (tid < 128) { mq = fabsf(1.f + qnw[tid]); mk = fabsf(1.f + knw[tid]); }
#pragma unroll
    for (int off = 32; off >= 1; off >>= 1) {
      mq = fmaxf(mq, __shfl_xor(mq, off, 64));
      mk = fmaxf(mk, __shfl_xor(mk, off, 64));
    }
    if (lane == 0) { s8[w * 2] = mq; s8[w * 2 + 1] = mk; }
    __syncthreads();
    if (tid == 0) {
      float MQ = fmaxf(s8[0], s8[2]), MK = fmaxf(s8[1], s8[3]);
      bshare = 16.3217f * MQ * MK * 1.02f + 0.1f;  // sqrt(128)*log2e + margin
    }
    __syncthreads();
  }
  const float B = bshare;
  const float CSC = 0.08838834764831845f * 1.44269504088896f;  // scale*log2e

  // per-lane q-norm weights for frag dims d = ks*32 + quad*8 + j
  float wq[4][8];
#pragma unroll
  for (int ks = 0; ks < 4; ++ks)
#pragma unroll
    for (int j = 0; j < 8; ++j) wq[ks][j] = 1.f + qnw[ks * 32 + quad * 8 + j];

#pragma unroll 1
  for (int sel = 0; sel < 2; ++sel) {
    const int qt = sel ? (31 - pb) : pb;
    const int q0 = qt * 64;
    const int ntl = (qt >= s) ? ((qt - s) / 3 + 1) : 0;  // tiles s, s+3, ...

    // ---- q load + RMSNorm + RoPE, fully in-register ----
    float qv[4][8];
    const ushort* qb = qg16 + ((size_t)(q0 + w * 16 + l15) * NH + h) * (2 * DH);
#pragma unroll
    for (int ks = 0; ks < 4; ++ks) {
      ushort4 u0 = *(const ushort4*)(qb + ks * 32 + quad * 8);
      ushort4 u1 = *(const ushort4*)(qb + ks * 32 + quad * 8 + 4);
      qv[ks][0] = bf2f(u0.x); qv[ks][1] = bf2f(u0.y);
      qv[ks][2] = bf2f(u0.z); qv[ks][3] = bf2f(u0.w);
      qv[ks][4] = bf2f(u1.x); qv[ks][5] = bf2f(u1.y);
      qv[ks][6] = bf2f(u1.z); qv[ks][7] = bf2f(u1.w);
    }
    float ss = 0.f;
#pragma unroll
    for (int ks = 0; ks < 4; ++ks)
#pragma unroll
      for (int j = 0; j < 8; ++j) ss += qv[ks][j] * qv[ks][j];
    ss += __shfl_xor(ss, 16, 64);
    ss += __shfl_xor(ss, 32, 64);
    const float inv = rsqrtf(ss * (1.f / 128.f) + 1e-6f);
    const float pos = (float)positions[q0 + w * 16 + l15];
    union { bf16x8 v; ushort u[8]; } qfu[4];
#pragma unroll
    for (int ks = 0; ks < 2; ++ks)
#pragma unroll
      for (int j = 0; j < 8; ++j) {
        int d = ks * 32 + quad * 8 + j;
        float rev = pos * exp2f((float)d * -0.20762050593045233f) *
                    0.15915494309189535f;
        float fr = rev - floorf(rev);
        float sn = __builtin_amdgcn_sinf(fr);
        float cs = __builtin_amdgcn_cosf(fr);
        float x1 = qv[ks][j] * inv * wq[ks][j];
        float x2 = qv[ks + 2][j] * inv * wq[ks + 2][j];
        qfu[ks].u[j]     = f2bf(x1 * cs - x2 * sn);
        qfu[ks + 2].u[j] = f2bf(x2 * cs + x1 * sn);
      }

    f32x4 oacc[9];
#pragma unroll
    for (int i = 0; i < 9; ++i) oacc[i] = (f32x4){0.f, 0.f, 0.f, 0.f};

#pragma unroll 1
    for (int it = 0; it < ntl; ++it) {
      const int kt = s + 3 * it;
      const int kt0 = kt * 64;
      __syncthreads();  // all waves done reading Ks/Vs (prev iter / prev sel)
      // stage K tile: 64 rows x 16 chunks (swizzle ^(row&15))
#pragma unroll
      for (int p = 0; p < 4; ++p) {
        int row = p * 16 + (tid >> 4), ch = tid & 15;
        int gch = ch ^ (row & 15);
        gld16(k16 + ((size_t)(kt0 + row) * NKV + kvh) * DH + gch * 8,
              Ks + (p * 256 + w * 64) * 8);
      }
      // stage V^T tile: 128 rows x 8 chunks (swizzle ^(row&7))
#pragma unroll
      for (int p = 0; p < 4; ++p) {
        int row = p * 32 + (tid >> 3), ch = tid & 7;
        int gch = ch ^ (row & 7);
        gld16(v16t + (size_t)(kvh * DH + row) * T_SEQ + kt0 + gch * 8,
              Vs + (p * 256 + w * 64) * 8);
      }
      __syncthreads();  // vmcnt drained -> tiles ready

      // S = Q K^T
      f32x4 sacc[4];
#pragma unroll
      for (int ni = 0; ni < 4; ++ni) sacc[ni] = (f32x4){0.f, 0.f, 0.f, 0.f};
#pragma unroll
      for (int ks = 0; ks < 4; ++ks)
#pragma unroll
        for (int ni = 0; ni < 4; ++ni) {
          int row = ni * 16 + l15;
          int pch = (ks * 4 + quad) ^ (row & 15);
          bf16x8 kf = *(const bf16x8*)(Ks + row * 128 + pch * 8);
          sacc[ni] = __builtin_amdgcn_mfma_f32_16x16x32_bf16(
              qfu[ks].v, kf, sacc[ni], 0, 0, 0);
        }

      // p = exp2(s*CSC - B); mask only on the diagonal tile
      const bool diag = (kt == qt);
#pragma unroll
      for (int ni = 0; ni < 4; ++ni) {
        int key = kt0 + ni * 16 + l15;
#pragma unroll
        for (int r = 0; r < 4; ++r) {
          float arg = fmaf(sacc[ni][r], CSC, -B);
          float pv;
          if (diag) {
            int q = q0 + w * 16 + quad * 4 + r;
            pv = (key <= q) ? exp2f(arg) : 0.f;
          } else {
            pv = exp2f(arg);
          }
          Ps[w][quad * 4 + r][ni * 16 + l15] = f2bf_rz(pv);
        }
      }

      // O += P V  (ni=8 tile: ones row -> row-sums accumulate in col 0)
#pragma unroll
      for (int ks2 = 0; ks2 < 2; ++ks2) {
        bf16x8 pf = *(const bf16x8*)(&Ps[w][l15][ks2 * 32 + quad * 8]);
#pragma unroll
        for (int ni = 0; ni < 9; ++ni) {
          int row = ni * 16 + l15;
          int pch = (ks2 * 4 + quad) ^ (row & 7);
          bf16x8 vf = *(const bf16x8*)(Vs + row * 64 + pch * 8);
          oacc[ni] = __builtin_amdgcn_mfma_f32_16x16x32_bf16(
              pf, vf, oacc[ni], 0, 0, 0);
        }
      }
    }

    // epilogue: write bf16 partial O ([h][q][d]) and fp32 partial l
    ushort* Op = (s == 0) ? Op0 : (s == 1) ? Op1 : Op2;
#pragma unroll
    for (int ni = 0; ni < 8; ++ni) {
      int d = ni * 16 + l15;
#pragma unroll
      for (int r = 0; r < 4; ++r) {
        int q = q0 + w * 16 + quad * 4 + r;
        Op[((size_t)h * T_SEQ + q) * DH + d] = f2bf(oacc[ni][r]);
      }
    }
    if (l15 == 0) {   // lane quad*16 holds l for its 4 rows in oacc[8]
#pragma unroll
      for (int r = 0; r < 4; ++r) {
        int q = q0 + w * 16 + quad * 4 + r;
        lpart[(size_t)s * (NH * T_SEQ) + h * T_SEQ + q] = oacc[8][r];
      }
    }
  }
}

// ---------------- combine: O=(ΣOp)/(Σl) * sigmoid(gate) -> ob16 ----------
__global__ __launch_bounds__(256) void combine_kernel(
    const ushort* __restrict__ Op0, const ushort* __restrict__ Op1,
    const ushort* __restrict__ Op2, const float* __restrict__ lpart,
    const ushort* __restrict__ qg16, ushort* __restrict__ ob16) {
  const int t = blockIdx.x, tid = threadIdx.x;
  const int h = tid >> 4, d0 = (tid & 15) * 8;
  const int NT = NH * T_SEQ;
  const float l = lpart[h * T_SEQ + t] + lpart[NT + h * T_SEQ + t] +
                  lpart[2 * NT + h * T_SEQ + t];
  const float inv = 1.0f / l;
  const size_t po = ((size_t)h * T_SEQ + t) * DH + d0;
  ushort4 a0 = *(const ushort4*)(Op0 + po);
  ushort4 a1 = *(const ushort4*)(Op0 + po + 4);
  ushort4 b0 = *(const ushort4*)(Op1 + po);
  ushort4 b1 = *(const ushort4*)(Op1 + po + 4);
  ushort4 c0 = *(const ushort4*)(Op2 + po);
  ushort4 c1 = *(const ushort4*)(Op2 + po + 4);
  const ushort* gp = qg16 + ((size_t)t * NH + h) * (2 * DH) + DH + d0;
  ushort4 g0 = *(const ushort4*)(gp);
  ushort4 g1 = *(const ushort4*)(gp + 4);
  float oa[8] = {bf2f(a0.x), bf2f(a0.y), bf2f(a0.z), bf2f(a0.w),
                 bf2f(a1.x), bf2f(a1.y), bf2f(a1.z), bf2f(a1.w)};
  float ob[8] = {bf2f(b0.x), bf2f(b0.y), bf2f(b0.z), bf2f(b0.w),
                 bf2f(b1.x), bf2f(b1.y), bf2f(b1.z), bf2f(b1.w)};
  float oc[8] = {bf2f(c0.x), bf2f(c0.y), bf2f(c0.z), bf2f(c0.w),
                 bf2f(c1.x), bf2f(c1.y), bf2f(c1.z), bf2f(c1.w)};
  float gg[8] = {bf2f(g0.x), bf2f(g0.y), bf2f(g0.z), bf2f(g0.w),
                 bf2f(g1.x), bf2f(g1.y), bf2f(g1.z), bf2f(g1.w)};
  ushort r[8];
#pragma unroll
  for (int i = 0; i < 8; ++i) {
    float o = (oa[i] + ob[i] + oc[i]) * inv;
    o = o / (1.0f + exp2f(-gg[i] * 1.44269504088896f));
    r[i] = f2bf(o);
  }
  ushort* op = ob16 + (size_t)t * (NH * DH) + h * DH + d0;
  *(ushort4*)(op)     = (ushort4){r[0], r[1], r[2], r[3]};
  *(ushort4*)(op + 4) = (ushort4){r[4], r[5], r[6], r[7]};
}

extern "C" void kernel_launch(void* const* d_in, const int* in_sizes, int n_in,
                              void* d_out, int out_size, void* d_ws, size_t ws_size,
                              hipStream_t stream) {
  const int*   positions = (const int*)d_in[0];
  const float* hs  = (const float*)d_in[1];
  const float* Wq  = (const float*)d_in[2];
  const float* Wk  = (const float*)d_in[3];
  const float* Wv  = (const float*)d_in[4];
  const float* Wo  = (const float*)d_in[5];
  const float* qnw = (const float*)d_in[6];
  const float* knw = (const float*)d_in[7];
  float* out = (float*)d_out;

  // workspace (64 MB), region reuse (MB offsets):
  // [0,16)  qg16 (qkv -> attn q + combine gate)
  // [16,24) hs16 (prep->qkv)           -> Op0   (attn->combine)
  // [24,40) Wqt  (prep->qkv)           -> Op1 [24,32), Op2 [32,40)
  // [40,44) kb16 (qkv->norm_k)         -> lpart (attn->combine)
  // [44,48) Wkt  (prep->qkv)           -> k16   (norm_k->attn)
  // [48,52) Wvt  (prep->qkv)           -> ob16 [48,56) (combine->out)
  // [52,56) v16t (qkv->attn)
  // [56,64) Wot  (prep->gemm_out)
  const size_t MB = 1 << 20;
  uint8_t* ws = (uint8_t*)d_ws;
  ushort* qg16 = (ushort*)(ws + 0);
  ushort* hs16 = (ushort*)(ws + 16 * MB);
  ushort* Op0  = (ushort*)(ws + 16 * MB);
  ushort* Wqt  = (ushort*)(ws + 24 * MB);
  ushort* Op1  = (ushort*)(ws + 24 * MB);
  ushort* Op2  = (ushort*)(ws + 32 * MB);
  ushort* kb16 = (ushort*)(ws + 40 * MB);
  float*  lpart= (float*)(ws + 40 * MB);
  ushort* Wkt  = (ushort*)(ws + 44 * MB);
  ushort* k16  = (ushort*)(ws + 44 * MB);
  ushort* Wvt  = (ushort*)(ws + 48 * MB);
  ushort* ob16 = (ushort*)(ws + 48 * MB);
  ushort* v16t = (ushort*)(ws + 52 * MB);
  ushort* Wot  = (ushort*)(ws + 56 * MB);

  prep_kernel<<<8192, 256, 0, stream>>>(hs, Wq, Wk, Wv, Wo,
                                        hs16, Wqt, Wkt, Wvt, Wot);
  gemm_qkv<<<768, 256, 0, stream>>>(hs16, Wqt, Wkt, Wvt, qg16, kb16, v16t);
  norm_k<<<dim3(T_SEQ, NKV), 128, 0, stream>>>(kb16, positions, knw, k16);
  attn_mfma<<<dim3(16, NH, 3), 256, 0, stream>>>(qg16, k16, v16t, positions,
                                                 qnw, knw, Op0, Op1, Op2, lpart);
  combine_kernel<<<T_SEQ, 256, 0, stream>>>(Op0, Op1, Op2, lpart, qg16, ob16);
  gemm_out<<<512, 256, 0, stream>>>(ob16, Wot, out);
}

// Round 7
// 286.399 us; speedup vs baseline: 7.0304x; 1.0107x over previous
//
#include <hip/hip_runtime.h>
#include <stdint.h>
#include <math.h>

// Problem constants
#define T_SEQ 2048
#define HID   2048
#define NH    16
#define NKV   8
#define DH    128

typedef __bf16 bf16x8 __attribute__((ext_vector_type(8)));
typedef float  f32x4  __attribute__((ext_vector_type(4)));

__device__ __forceinline__ ushort f2bf(float f) {   // round-to-nearest-even
  uint32_t u = __float_as_uint(f);
  u += 0x7FFF + ((u >> 16) & 1);
  return (ushort)(u >> 16);
}
__device__ __forceinline__ ushort f2bf_rz(float f) {  // truncate (Ps; bias cancels in o/l)
  return (ushort)(__float_as_uint(f) >> 16);
}
__device__ __forceinline__ float bf2f(ushort u) {
  return __uint_as_float(((uint32_t)u) << 16);
}
// async global->LDS, 16B per lane; LDS dest = wave-uniform base + lane*16
__device__ __forceinline__ void gld16(const void* g, void* l) {
  __builtin_amdgcn_global_load_lds(
      (const __attribute__((address_space(1))) uint32_t*)g,
      (__attribute__((address_space(3))) uint32_t*)l, 16, 0, 0);
}

// ---------------- prep: hs conv + all W transposes (64x64 tiles) ----------
// flat grid: [0,4096) conv hs; [4096,6144) Wq^T; [6144,6656) Wk^T;
// [6656,7168) Wv^T; [7168,8192) Wo^T.
__global__ __launch_bounds__(256) void prep_kernel(
    const float* __restrict__ hs, const float* __restrict__ Wq,
    const float* __restrict__ Wk, const float* __restrict__ Wv,
    const float* __restrict__ Wo, ushort* __restrict__ hs16,
    ushort* __restrict__ Wqt, ushort* __restrict__ Wkt,
    ushort* __restrict__ Wvt, ushort* __restrict__ Wot) {
  int bid = blockIdx.x;
  if (bid < 4096) {  // conv hs -> bf16
    int i = (bid * 256 + threadIdx.x) * 4;
    float4 v = *(const float4*)(hs + i);
    ushort4 o = {f2bf(v.x), f2bf(v.y), f2bf(v.z), f2bf(v.w)};
    *(ushort4*)(hs16 + i) = o;
    return;
  }
  bid -= 4096;
  const float* src; ushort* dst; int N, bi, bj;
  if (bid < 2048)      { src = Wq; dst = Wqt; N = 4096; bj = bid & 63; bi = bid >> 6; }
  else if (bid < 2560) { bid -= 2048; src = Wk; dst = Wkt; N = 1024; bj = bid & 15; bi = bid >> 4; }
  else if (bid < 3072) { bid -= 2560; src = Wv; dst = Wvt; N = 1024; bj = bid & 15; bi = bid >> 4; }
  else                 { bid -= 3072; src = Wo; dst = Wot; N = 2048; bj = bid & 31; bi = bid >> 5; }
  __shared__ float tile[64][65];
  const int r = threadIdx.x >> 2, cg = (threadIdx.x & 3) * 16;
  const float* sp = src + (size_t)(bi * 64 + r) * N + bj * 64 + cg;
#pragma unroll
  for (int p = 0; p < 4; ++p) {
    float4 v = *(const float4*)(sp + p * 4);
    tile[r][cg + p * 4 + 0] = v.x; tile[r][cg + p * 4 + 1] = v.y;
    tile[r][cg + p * 4 + 2] = v.z; tile[r][cg + p * 4 + 3] = v.w;
  }
  __syncthreads();
  ushort* dp = dst + (size_t)(bj * 64 + r) * HID + bi * 64 + cg;
#pragma unroll
  for (int p = 0; p < 2; ++p) {
    union { uint4 v; ushort u[8]; } o;
#pragma unroll
    for (int j = 0; j < 8; ++j) o.u[j] = f2bf(tile[cg + p * 8 + j][r]);
    *(uint4*)(dp + p * 8) = o.v;
  }
}

// ---------------- bf16 MFMA GEMM K-loop: acc += A[m0:,:] @ Bt[n0:,:]^T ----
// MI = m-frags/wave. REMAP=1: wave covers B-cols {p32..p32+31, 64+p32..}
// (p32=(w&1)*32) so RoPE pairs (d, d+64) sit in-lane at frags (ni, ni+2).
template <int MI, int REMAP>
__device__ __forceinline__ void gemm_loop(
    const ushort* __restrict__ A, const ushort* __restrict__ Bt,
    int K, int m0, int n0, ushort* As, ushort* Bs, f32x4 (*acc)[4]) {
  const int tid = threadIdx.x, lane = tid & 63, w = tid >> 6;
  const int quad = lane >> 4, l15 = lane & 15;
  const int wm = (w >> 1) * (MI * 16), wn = (w & 1) * 64, p32 = (w & 1) * 32;
  const int srow = tid >> 2, sch = tid & 3;
  for (int k0 = 0; k0 < K; k0 += 32) {
    __syncthreads();
#pragma unroll
    for (int p = 0; p < MI / 2; ++p) {
      int row = p * 64 + srow;
      int gch = sch ^ ((row >> 1) & 3);
      gld16(A + (size_t)(m0 + row) * K + k0 + gch * 8,
            As + (p * 256 + w * 64) * 8);
    }
#pragma unroll
    for (int p = 0; p < 2; ++p) {
      int row = p * 64 + srow;
      int gch = sch ^ ((row >> 1) & 3);
      gld16(Bt + (size_t)(n0 + row) * K + k0 + gch * 8,
            Bs + (p * 256 + w * 64) * 8);
    }
    __syncthreads();
    bf16x8 af[MI], bfr[4];
#pragma unroll
    for (int mi = 0; mi < MI; ++mi) {
      int row = wm + mi * 16 + l15;
      int pch = quad ^ ((row >> 1) & 3);
      af[mi] = *(const bf16x8*)(As + row * 32 + pch * 8);
    }
#pragma unroll
    for (int ni = 0; ni < 4; ++ni) {
      int row = REMAP ? ((ni >> 1) * 64 + p32 + (ni & 1) * 16 + l15)
                      : (wn + ni * 16 + l15);
      int pch = quad ^ ((row >> 1) & 3);
      bfr[ni] = *(const bf16x8*)(Bs + row * 32 + pch * 8);
    }
#pragma unroll
    for (int mi = 0; mi < MI; ++mi)
#pragma unroll
      for (int ni = 0; ni < 4; ++ni)
        acc[mi][ni] = __builtin_amdgcn_mfma_f32_16x16x32_bf16(
            af[mi], bfr[ni], acc[mi][ni], 0, 0, 0);
  }
}

// remapped col of frag ni (REMAP=1 layout)
__device__ __forceinline__ int rcol(int ni) {
  return (ni >> 1) * 64 + ((threadIdx.x >> 6) & 1) * 32 + (ni & 1) * 16 +
         (threadIdx.x & 15);
}

// bf16 tile store for REMAP layout (row = wm + mi*16 + quad*4 + r)
__device__ __forceinline__ void bf16_store_r(f32x4 (*acc)[4],
                                             ushort* __restrict__ Cb,
                                             int Ncols, int m0, int n0) {
  const int lane = threadIdx.x & 63, w = threadIdx.x >> 6;
  const int quad = lane >> 4;
  const int wm = (w >> 1) * 64;
#pragma unroll
  for (int mi = 0; mi < 4; ++mi)
#pragma unroll
    for (int ni = 0; ni < 4; ++ni)
#pragma unroll
      for (int r = 0; r < 4; ++r) {
        int row = m0 + wm + mi * 16 + quad * 4 + r;
        int col = n0 + rcol(ni);
        Cb[(size_t)row * Ncols + col] = f2bf(acc[mi][ni][r]);
      }
}

// Fully in-register RMSNorm + RoPE epilogue (REMAP layout). Row-sums via
// l15 shuffles + 1KB cross-wave LDS exchange (overlays dead staging LDS).
__device__ __forceinline__ void nr_epilogue(
    f32x4 (*acc)[4], const float* __restrict__ wgt,
    const int* __restrict__ positions, int m0, ushort* __restrict__ outp,
    int ostride, float* psld /* >=256 floats */) {
  const int lane = threadIdx.x & 63, w = threadIdx.x >> 6;
  const int quad = lane >> 4, l15 = lane & 15;
  const int wm = (w >> 1) * 64, p32 = (w & 1) * 32;
  float rs[4][4];
#pragma unroll
  for (int mi = 0; mi < 4; ++mi)
#pragma unroll
    for (int r = 0; r < 4; ++r) {
      float s = 0.f;
#pragma unroll
      for (int ni = 0; ni < 4; ++ni) { float v = acc[mi][ni][r]; s += v * v; }
#pragma unroll
      for (int off = 1; off <= 8; off <<= 1) s += __shfl_xor(s, off, 64);
      rs[mi][r] = s;
    }
  __syncthreads();  // all waves done with staging LDS -> safe to overlay
  if (l15 == 0) {
#pragma unroll
    for (int mi = 0; mi < 4; ++mi)
#pragma unroll
      for (int r = 0; r < 4; ++r)
        psld[(wm + mi * 16 + quad * 4 + r) * 2 + (w & 1)] = rs[mi][r];
  }
  __syncthreads();
  float wv[4];
#pragma unroll
  for (int ni = 0; ni < 4; ++ni) wv[ni] = 1.f + wgt[rcol(ni)];
#pragma unroll
  for (int mi = 0; mi < 4; ++mi)
#pragma unroll
    for (int r = 0; r < 4; ++r) {
      int row = wm + mi * 16 + quad * 4 + r;
      int t = m0 + row;
      float inv = rsqrtf((psld[row * 2] + psld[row * 2 + 1]) * (1.f / 128.f) +
                         1e-6f);
      float pos = (float)positions[t];
      ushort* op = outp + (size_t)t * ostride;
#pragma unroll
      for (int ni = 0; ni < 2; ++ni) {
        int d = p32 + ni * 16 + l15;  // in [0,64); pair at d+64 = frag ni+2
        // angle in revolutions: pos * 10000^(-d/64) / (2*pi)
        float rev = pos * exp2f((float)d * -0.20762050593045233f) *
                    0.15915494309189535f;
        float fr = rev - floorf(rev);
        float sn = __builtin_amdgcn_sinf(fr);
        float cs = __builtin_amdgcn_cosf(fr);
        float x1 = acc[mi][ni][r] * inv * wv[ni];
        float x2 = acc[mi][ni + 2][r] * inv * wv[ni + 2];
        op[d]      = f2bf(x1 * cs - x2 * sn);
        op[d + 64] = f2bf(x2 * cs + x1 * sn);
      }
    }
}

// Fused QKV projections + q/k RMSNorm+RoPE (in-register epilogue).
// [0,512): Q (even nt -> normed q16, odd nt -> gate16);
// [512,640): K -> normed k16; [640,768): V^T -> v16t.
__global__ __launch_bounds__(256) void gemm_qkv(
    const ushort* __restrict__ hs16, const ushort* __restrict__ Wqt,
    const ushort* __restrict__ Wkt, const ushort* __restrict__ Wvt,
    const int* __restrict__ positions, const float* __restrict__ qnw,
    const float* __restrict__ knw, ushort* __restrict__ q16,
    ushort* __restrict__ gate16, ushort* __restrict__ k16,
    ushort* __restrict__ v16t) {
  __shared__ ushort As[128 * 32];
  __shared__ ushort Bs[128 * 32];
  f32x4 acc[4][4];
#pragma unroll
  for (int i = 0; i < 4; ++i)
#pragma unroll
    for (int j = 0; j < 4; ++j) acc[i][j] = (f32x4){0.f, 0.f, 0.f, 0.f};
  const int b = blockIdx.x;
  if (b < 512) {
    int mt = b >> 5, nt = b & 31, m0 = mt * 128, h = nt >> 1;
    gemm_loop<4, 1>(hs16, Wqt, HID, m0, nt * 128, As, Bs, acc);
    if ((nt & 1) == 0)
      nr_epilogue(acc, qnw, positions, m0, q16 + h * DH, NH * DH, (float*)As);
    else
      bf16_store_r(acc, gate16, NH * DH, m0, h * DH);
  } else if (b < 640) {
    int f = b - 512, mt = f >> 3, nt = f & 7, m0 = mt * 128;
    gemm_loop<4, 1>(hs16, Wkt, HID, m0, nt * 128, As, Bs, acc);
    nr_epilogue(acc, knw, positions, m0, k16 + nt * DH, NKV * DH, (float*)As);
  } else {
    int f = b - 640, m0 = (f >> 4) * 128, n0 = (f & 15) * 128;
    gemm_loop<4, 1>(Wvt, hs16, HID, m0, n0, As, Bs, acc);
    bf16_store_r(acc, v16t, T_SEQ, m0, n0);
  }
}

// Output projection: 64x128 tiles (512 blocks = 2/CU).
__global__ __launch_bounds__(256) void gemm_out(
    const ushort* __restrict__ ob16, const ushort* __restrict__ Wot,
    float* __restrict__ out) {
  __shared__ ushort As[64 * 32];
  __shared__ ushort Bs[128 * 32];
  f32x4 acc[2][4];
#pragma unroll
  for (int i = 0; i < 2; ++i)
#pragma unroll
    for (int j = 0; j < 4; ++j) acc[i][j] = (f32x4){0.f, 0.f, 0.f, 0.f};
  const int b = blockIdx.x;
  const int m0 = (b >> 4) * 64, n0 = (b & 15) * 128;
  gemm_loop<2, 0>(ob16, Wot, HID, m0, n0, As, Bs, acc);
  const int lane = threadIdx.x & 63, w = threadIdx.x >> 6;
  const int quad = lane >> 4, l15 = lane & 15;
  const int wm = (w >> 1) * 32, wn = (w & 1) * 64;
#pragma unroll
  for (int mi = 0; mi < 2; ++mi)
#pragma unroll
    for (int ni = 0; ni < 4; ++ni)
#pragma unroll
      for (int r = 0; r < 4; ++r) {
        int row = m0 + wm + mi * 16 + quad * 4 + r;
        int col = n0 + wn + ni * 16 + l15;
        out[(size_t)row * HID + col] = acc[mi][ni][r];
      }
}

// ---------------- MFMA flash attention, key-split x3, single-buffer -------
// grid (16, NH, 3): block (pb,h,s) does q-tiles {pb, 31-pb}, k-tiles
// kt ≡ s (mod 3). q16/k16 arrive pre-normed+roped. Static softmax bound B
// -> partials summable; combine_kernel merges the 3 splits.
__global__ __launch_bounds__(256) void attn_mfma(
    const ushort* __restrict__ q16, const ushort* __restrict__ k16,
    const ushort* __restrict__ v16t, const float* __restrict__ qnw,
    const float* __restrict__ knw, ushort* __restrict__ Op0,
    ushort* __restrict__ Op1, ushort* __restrict__ Op2,
    float* __restrict__ lpart) {
  const int pb = blockIdx.x, h = blockIdx.y, s = blockIdx.z, kvh = h >> 1;
  const int tid = threadIdx.x, lane = tid & 63, w = tid >> 6;
  const int quad = lane >> 4, l15 = lane & 15;

  __shared__ ushort Ks[64 * 128];     // 16 KB
  __shared__ ushort Vs[144 * 64];     // 18 KB; rows 128..143 constant
  __shared__ ushort Ps[4][16][72];    // 9.2 KB, per-wave

  // constant rows of Vs: row 128 = 1.0 (row-sum via MFMA), 129..143 = 0
  for (int i = tid; i < 16 * 64; i += 256) {
    int row = 128 + (i >> 6), col = i & 63;
    Vs[row * 64 + col] = (row == 128) ? (ushort)0x3F80 : (ushort)0;
  }

  // score bound B (log2 domain)
  __shared__ float s8[8];
  __shared__ float bshare;
  {
    float mq = 0.f, mk = 0.f;
    if (tid < 128) { mq = fabsf(1.f + qnw[tid]); mk = fabsf(1.f + knw[tid]); }
#pragma unroll
    for (int off = 32; off >= 1; off >>= 1) {
      mq = fmaxf(mq, __shfl_xor(mq, off, 64));
      mk = fmaxf(mk, __shfl_xor(mk, off, 64));
    }
    if (lane == 0) { s8[w * 2] = mq; s8[w * 2 + 1] = mk; }
    __syncthreads();
    if (tid == 0) {
      float MQ = fmaxf(s8[0], s8[2]), MK = fmaxf(s8[1], s8[3]);
      bshare = 16.3217f * MQ * MK * 1.02f + 0.1f;  // sqrt(128)*log2e + margin
    }
    __syncthreads();
  }
  const float B = bshare;
  const float CSC = 0.08838834764831845f * 1.44269504088896f;  // scale*log2e

#pragma unroll 1
  for (int sel = 0; sel < 2; ++sel) {
    const int qt = sel ? (31 - pb) : pb;
    const int q0 = qt * 64;
    const int ntl = (qt >= s) ? ((qt - s) / 3 + 1) : 0;  // tiles s, s+3, ...

    bf16x8 qf[4];
    const ushort* qbase = q16 + ((size_t)(q0 + w * 16 + l15) * NH + h) * DH;
#pragma unroll
    for (int ks = 0; ks < 4; ++ks)
      qf[ks] = *(const bf16x8*)(qbase + ks * 32 + quad * 8);

    f32x4 oacc[9];
#pragma unroll
    for (int i = 0; i < 9; ++i) oacc[i] = (f32x4){0.f, 0.f, 0.f, 0.f};

#pragma unroll 1
    for (int it = 0; it < ntl; ++it) {
      const int kt = s + 3 * it;
      const int kt0 = kt * 64;
      __syncthreads();  // all waves done reading Ks/Vs (prev iter / prev sel)
      // stage K tile: 64 rows x 16 chunks (swizzle ^(row&15))
#pragma unroll
      for (int p = 0; p < 4; ++p) {
        int row = p * 16 + (tid >> 4), ch = tid & 15;
        int gch = ch ^ (row & 15);
        gld16(k16 + ((size_t)(kt0 + row) * NKV + kvh) * DH + gch * 8,
              Ks + (p * 256 + w * 64) * 8);
      }
      // stage V^T tile: 128 rows x 8 chunks (swizzle ^(row&7))
#pragma unroll
      for (int p = 0; p < 4; ++p) {
        int row = p * 32 + (tid >> 3), ch = tid & 7;
        int gch = ch ^ (row & 7);
        gld16(v16t + (size_t)(kvh * DH + row) * T_SEQ + kt0 + gch * 8,
              Vs + (p * 256 + w * 64) * 8);
      }
      __syncthreads();  // vmcnt drained -> tiles ready

      // S = Q K^T
      f32x4 sacc[4];
#pragma unroll
      for (int ni = 0; ni < 4; ++ni) sacc[ni] = (f32x4){0.f, 0.f, 0.f, 0.f};
#pragma unroll
      for (int ks = 0; ks < 4; ++ks)
#pragma unroll
        for (int ni = 0; ni < 4; ++ni) {
          int row = ni * 16 + l15;
          int pch = (ks * 4 + quad) ^ (row & 15);
          bf16x8 kf = *(const bf16x8*)(Ks + row * 128 + pch * 8);
          sacc[ni] = __builtin_amdgcn_mfma_f32_16x16x32_bf16(
              qf[ks], kf, sacc[ni], 0, 0, 0);
        }

      // p = exp2(s*CSC - B); mask only on the diagonal tile
      const bool diag = (kt == qt);
#pragma unroll
      for (int ni = 0; ni < 4; ++ni) {
        int key = kt0 + ni * 16 + l15;
#pragma unroll
        for (int r = 0; r < 4; ++r) {
          float arg = fmaf(sacc[ni][r], CSC, -B);
          float pv;
          if (diag) {
            int q = q0 + w * 16 + quad * 4 + r;
            pv = (key <= q) ? exp2f(arg) : 0.f;
          } else {
            pv = exp2f(arg);
          }
          Ps[w][quad * 4 + r][ni * 16 + l15] = f2bf_rz(pv);
        }
      }

      // O += P V  (ni=8 tile: ones row -> row-sums accumulate in col 0)
#pragma unroll
      for (int ks2 = 0; ks2 < 2; ++ks2) {
        bf16x8 pf = *(const bf16x8*)(&Ps[w][l15][ks2 * 32 + quad * 8]);
#pragma unroll
        for (int ni = 0; ni < 9; ++ni) {
          int row = ni * 16 + l15;
          int pch = (ks2 * 4 + quad) ^ (row & 7);
          bf16x8 vf = *(const bf16x8*)(Vs + row * 64 + pch * 8);
          oacc[ni] = __builtin_amdgcn_mfma_f32_16x16x32_bf16(
              pf, vf, oacc[ni], 0, 0, 0);
        }
      }
    }

    // epilogue: write bf16 partial O ([h][q][d]) and fp32 partial l
    ushort* Op = (s == 0) ? Op0 : (s == 1) ? Op1 : Op2;
#pragma unroll
    for (int ni = 0; ni < 8; ++ni) {
      int d = ni * 16 + l15;
#pragma unroll
      for (int r = 0; r < 4; ++r) {
        int q = q0 + w * 16 + quad * 4 + r;
        Op[((size_t)h * T_SEQ + q) * DH + d] = f2bf(oacc[ni][r]);
      }
    }
    if (l15 == 0) {   // lane quad*16 holds l for its 4 rows in oacc[8]
#pragma unroll
      for (int r = 0; r < 4; ++r) {
        int q = q0 + w * 16 + quad * 4 + r;
        lpart[(size_t)s * (NH * T_SEQ) + h * T_SEQ + q] = oacc[8][r];
      }
    }
  }
}

// ---------------- combine: O=(ΣOp)/(Σl) * sigmoid(gate) -> ob16 ----------
__global__ __launch_bounds__(256) void combine_kernel(
    const ushort* __restrict__ Op0, const ushort* __restrict__ Op1,
    const ushort* __restrict__ Op2, const float* __restrict__ lpart,
    const ushort* __restrict__ gate16, ushort* __restrict__ ob16) {
  const int t = blockIdx.x, tid = threadIdx.x;
  const int h = tid >> 4, d0 = (tid & 15) * 8;
  const int NT = NH * T_SEQ;
  const float l = lpart[h * T_SEQ + t] + lpart[NT + h * T_SEQ + t] +
                  lpart[2 * NT + h * T_SEQ + t];
  const float inv = 1.0f / l;
  const size_t po = ((size_t)h * T_SEQ + t) * DH + d0;
  ushort4 a0 = *(const ushort4*)(Op0 + po);
  ushort4 a1 = *(const ushort4*)(Op0 + po + 4);
  ushort4 b0 = *(const ushort4*)(Op1 + po);
  ushort4 b1 = *(const ushort4*)(Op1 + po + 4);
  ushort4 c0 = *(const ushort4*)(Op2 + po);
  ushort4 c1 = *(const ushort4*)(Op2 + po + 4);
  const ushort* gp = gate16 + (size_t)t * (NH * DH) + h * DH + d0;
  ushort4 g0 = *(const ushort4*)(gp);
  ushort4 g1 = *(const ushort4*)(gp + 4);
  float oa[8] = {bf2f(a0.x), bf2f(a0.y), bf2f(a0.z), bf2f(a0.w),
                 bf2f(a1.x), bf2f(a1.y), bf2f(a1.z), bf2f(a1.w)};
  float ob[8] = {bf2f(b0.x), bf2f(b0.y), bf2f(b0.z), bf2f(b0.w),
                 bf2f(b1.x), bf2f(b1.y), bf2f(b1.z), bf2f(b1.w)};
  float oc[8] = {bf2f(c0.x), bf2f(c0.y), bf2f(c0.z), bf2f(c0.w),
                 bf2f(c1.x), bf2f(c1.y), bf2f(c1.z), bf2f(c1.w)};
  float gg[8] = {bf2f(g0.x), bf2f(g0.y), bf2f(g0.z), bf2f(g0.w),
                 bf2f(g1.x), bf2f(g1.y), bf2f(g1.z), bf2f(g1.w)};
  ushort r[8];
#pragma unroll
  for (int i = 0; i < 8; ++i) {
    float o = (oa[i] + ob[i] + oc[i]) * inv;
    o = o / (1.0f + exp2f(-gg[i] * 1.44269504088896f));
    r[i] = f2bf(o);
  }
  ushort* op = ob16 + (size_t)t * (NH * DH) + h * DH + d0;
  *(ushort4*)(op)     = (ushort4){r[0], r[1], r[2], r[3]};
  *(ushort4*)(op + 4) = (ushort4){r[4], r[5], r[6], r[7]};
}

extern "C" void kernel_launch(void* const* d_in, const int* in_sizes, int n_in,
                              void* d_out, int out_size, void* d_ws, size_t ws_size,
                              hipStream_t stream) {
  const int*   positions = (const int*)d_in[0];
  const float* hs  = (const float*)d_in[1];
  const float* Wq  = (const float*)d_in[2];
  const float* Wk  = (const float*)d_in[3];
  const float* Wv  = (const float*)d_in[4];
  const float* Wo  = (const float*)d_in[5];
  const float* Wo_ = Wo; (void)Wo_;
  const float* qnw = (const float*)d_in[6];
  const float* knw = (const float*)d_in[7];
  float* out = (float*)d_out;

  // workspace (64 MB), region reuse (MB offsets):
  // [0,8)   hs16 (prep->qkv)   -> Op0  (attn->combine)
  // [8,24)  Wqt  (prep->qkv)   -> Op1 [8,16), Op2 [16,24)
  // [24,28) Wkt  (prep->qkv)   -> ob16 [24,32) (combine->gemm_out)
  // [28,32) Wvt  (prep->qkv)
  // [32,36) v16t (qkv->attn)
  // [36,40) k16  (qkv->attn)
  // [40,48) q16  (qkv->attn)
  // [48,56) gate16 (qkv->combine)
  // [56,64) Wot  (prep->gemm_out)
  // lpart lives in d_out (16 MB fp32, dead until gemm_out overwrites it).
  const size_t MB = 1 << 20;
  uint8_t* ws = (uint8_t*)d_ws;
  ushort* hs16  = (ushort*)(ws + 0);
  ushort* Op0   = (ushort*)(ws + 0);
  ushort* Wqt   = (ushort*)(ws + 8 * MB);
  ushort* Op1   = (ushort*)(ws + 8 * MB);
  ushort* Op2   = (ushort*)(ws + 16 * MB);
  ushort* Wkt   = (ushort*)(ws + 24 * MB);
  ushort* ob16  = (ushort*)(ws + 24 * MB);
  ushort* Wvt   = (ushort*)(ws + 28 * MB);
  ushort* v16t  = (ushort*)(ws + 32 * MB);
  ushort* k16   = (ushort*)(ws + 36 * MB);
  ushort* q16   = (ushort*)(ws + 40 * MB);
  ushort* gate16= (ushort*)(ws + 48 * MB);
  ushort* Wot   = (ushort*)(ws + 56 * MB);
  float*  lpart = (float*)d_out;   // scratch until gemm_out writes out

  prep_kernel<<<8192, 256, 0, stream>>>(hs, Wq, Wk, Wv, Wo,
                                        hs16, Wqt, Wkt, Wvt, Wot);
  gemm_qkv<<<768, 256, 0, stream>>>(hs16, Wqt, Wkt, Wvt, positions, qnw, knw,
                                    q16, gate16, k16, v16t);
  attn_mfma<<<dim3(16, NH, 3), 256, 0, stream>>>(q16, k16, v16t, qnw, knw,
                                                 Op0, Op1, Op2, lpart);
  combine_kernel<<<T_SEQ, 256, 0, stream>>>(Op0, Op1, Op2, lpart, gate16, ob16);
  gemm_out<<<512, 256, 0, stream>>>(ob16, Wot, out);
}

// Round 8
// 277.437 us; speedup vs baseline: 7.2575x; 1.0323x over previous
//
#include <hip/hip_runtime.h>
#include <stdint.h>
#include <math.h>

// Problem constants
#define T_SEQ 2048
#define HID   2048
#define NH    16
#define NKV   8
#define DH    128

typedef __bf16 bf16x8 __attribute__((ext_vector_type(8)));
typedef float  f32x4  __attribute__((ext_vector_type(4)));

__device__ __forceinline__ ushort f2bf(float f) {   // round-to-nearest-even
  uint32_t u = __float_as_uint(f);
  u += 0x7FFF + ((u >> 16) & 1);
  return (ushort)(u >> 16);
}
__device__ __forceinline__ ushort f2bf_rz(float f) {  // truncate (Ps; bias cancels in o/l)
  return (ushort)(__float_as_uint(f) >> 16);
}
__device__ __forceinline__ float bf2f(ushort u) {
  return __uint_as_float(((uint32_t)u) << 16);
}
// async global->LDS, 16B per lane; LDS dest = wave-uniform base + lane*16
__device__ __forceinline__ void gld16(const void* g, void* l) {
  __builtin_amdgcn_global_load_lds(
      (const __attribute__((address_space(1))) uint32_t*)g,
      (__attribute__((address_space(3))) uint32_t*)l, 16, 0, 0);
}

// ---------------- prep: hs conv + all W transposes (64x64 tiles) ----------
// flat grid: [0,4096) conv hs; [4096,6144) Wq^T; [6144,6656) Wk^T;
// [6656,7168) Wv^T; [7168,8192) Wo^T.
__global__ __launch_bounds__(256) void prep_kernel(
    const float* __restrict__ hs, const float* __restrict__ Wq,
    const float* __restrict__ Wk, const float* __restrict__ Wv,
    const float* __restrict__ Wo, ushort* __restrict__ hs16,
    ushort* __restrict__ Wqt, ushort* __restrict__ Wkt,
    ushort* __restrict__ Wvt, ushort* __restrict__ Wot) {
  int bid = blockIdx.x;
  if (bid < 4096) {  // conv hs -> bf16
    int i = (bid * 256 + threadIdx.x) * 4;
    float4 v = *(const float4*)(hs + i);
    ushort4 o = {f2bf(v.x), f2bf(v.y), f2bf(v.z), f2bf(v.w)};
    *(ushort4*)(hs16 + i) = o;
    return;
  }
  bid -= 4096;
  const float* src; ushort* dst; int N, bi, bj;
  if (bid < 2048)      { src = Wq; dst = Wqt; N = 4096; bj = bid & 63; bi = bid >> 6; }
  else if (bid < 2560) { bid -= 2048; src = Wk; dst = Wkt; N = 1024; bj = bid & 15; bi = bid >> 4; }
  else if (bid < 3072) { bid -= 2560; src = Wv; dst = Wvt; N = 1024; bj = bid & 15; bi = bid >> 4; }
  else                 { bid -= 3072; src = Wo; dst = Wot; N = 2048; bj = bid & 31; bi = bid >> 5; }
  __shared__ float tile[64][65];
  const int r = threadIdx.x >> 2, cg = (threadIdx.x & 3) * 16;
  const float* sp = src + (size_t)(bi * 64 + r) * N + bj * 64 + cg;
#pragma unroll
  for (int p = 0; p < 4; ++p) {
    float4 v = *(const float4*)(sp + p * 4);
    tile[r][cg + p * 4 + 0] = v.x; tile[r][cg + p * 4 + 1] = v.y;
    tile[r][cg + p * 4 + 2] = v.z; tile[r][cg + p * 4 + 3] = v.w;
  }
  __syncthreads();
  ushort* dp = dst + (size_t)(bj * 64 + r) * HID + bi * 64 + cg;
#pragma unroll
  for (int p = 0; p < 2; ++p) {
    union { uint4 v; ushort u[8]; } o;
#pragma unroll
    for (int j = 0; j < 8; ++j) o.u[j] = f2bf(tile[cg + p * 8 + j][r]);
    *(uint4*)(dp + p * 8) = o.v;
  }
}

// ---------------- bf16 MFMA GEMM K-loop: acc += A[m0:,:] @ Bt[n0:,:]^T ----
// MI = m-frags per wave (4 -> 128-row tile, 2 -> 64-row tile). N-tile = 128.
template <int MI>
__device__ __forceinline__ void gemm_loop(
    const ushort* __restrict__ A, const ushort* __restrict__ Bt,
    int K, int m0, int n0, ushort* As, ushort* Bs, f32x4 (*acc)[4]) {
  const int tid = threadIdx.x, lane = tid & 63, w = tid >> 6;
  const int quad = lane >> 4, l15 = lane & 15;
  const int wm = (w >> 1) * (MI * 16), wn = (w & 1) * 64;
  const int srow = tid >> 2, sch = tid & 3;
  for (int k0 = 0; k0 < K; k0 += 32) {
    __syncthreads();
#pragma unroll
    for (int p = 0; p < MI / 2; ++p) {
      int row = p * 64 + srow;
      int gch = sch ^ ((row >> 1) & 3);
      gld16(A + (size_t)(m0 + row) * K + k0 + gch * 8,
            As + (p * 256 + w * 64) * 8);
    }
#pragma unroll
    for (int p = 0; p < 2; ++p) {
      int row = p * 64 + srow;
      int gch = sch ^ ((row >> 1) & 3);
      gld16(Bt + (size_t)(n0 + row) * K + k0 + gch * 8,
            Bs + (p * 256 + w * 64) * 8);
    }
    __syncthreads();
    bf16x8 af[MI], bfr[4];
#pragma unroll
    for (int mi = 0; mi < MI; ++mi) {
      int row = wm + mi * 16 + l15;
      int pch = quad ^ ((row >> 1) & 3);
      af[mi] = *(const bf16x8*)(As + row * 32 + pch * 8);
    }
#pragma unroll
    for (int ni = 0; ni < 4; ++ni) {
      int row = wn + ni * 16 + l15;
      int pch = quad ^ ((row >> 1) & 3);
      bfr[ni] = *(const bf16x8*)(Bs + row * 32 + pch * 8);
    }
#pragma unroll
    for (int mi = 0; mi < MI; ++mi)
#pragma unroll
      for (int ni = 0; ni < 4; ++ni)
        acc[mi][ni] = __builtin_amdgcn_mfma_f32_16x16x32_bf16(
            af[mi], bfr[ni], acc[mi][ni], 0, 0, 0);
  }
}

// bf16 tile store (C/D layout: col = l15, row = quad*4 + reg)
__device__ __forceinline__ void bf16_store(f32x4 (*acc)[4],
                                           ushort* __restrict__ Cb, int Ncols,
                                           int m0, int n0) {
  const int lane = threadIdx.x & 63, w = threadIdx.x >> 6;
  const int quad = lane >> 4, l15 = lane & 15;
  const int wm = (w >> 1) * 64, wn = (w & 1) * 64;
#pragma unroll
  for (int mi = 0; mi < 4; ++mi)
#pragma unroll
    for (int ni = 0; ni < 4; ++ni)
#pragma unroll
      for (int r = 0; r < 4; ++r) {
        int row = m0 + wm + mi * 16 + quad * 4 + r;
        int col = n0 + wn + ni * 16 + l15;
        Cb[(size_t)row * Ncols + col] = f2bf(acc[mi][ni][r]);
      }
}

// Fused QKV projections (lean — zero epilogue; VGPR<=76 is the contract).
// [0,512): Q (even nt -> q16, odd nt -> gate16, both [t][h][128]);
// [512,640): K -> k16; [640,768): V^T -> v16t.
__global__ __launch_bounds__(256) void gemm_qkv(
    const ushort* __restrict__ hs16, const ushort* __restrict__ Wqt,
    const ushort* __restrict__ Wkt, const ushort* __restrict__ Wvt,
    ushort* __restrict__ q16, ushort* __restrict__ gate16,
    ushort* __restrict__ k16, ushort* __restrict__ v16t) {
  __shared__ ushort As[128 * 32];
  __shared__ ushort Bs[128 * 32];
  f32x4 acc[4][4];
#pragma unroll
  for (int i = 0; i < 4; ++i)
#pragma unroll
    for (int j = 0; j < 4; ++j) acc[i][j] = (f32x4){0.f, 0.f, 0.f, 0.f};
  const int b = blockIdx.x;
  if (b < 512) {
    int mt = b >> 5, nt = b & 31, m0 = mt * 128;
    gemm_loop<4>(hs16, Wqt, HID, m0, nt * 128, As, Bs, acc);
    ushort* dst = ((nt & 1) == 0) ? q16 : gate16;
    bf16_store(acc, dst, NH * DH, m0, (nt >> 1) * 128);
  } else if (b < 640) {
    int f = b - 512, m0 = (f >> 3) * 128, n0 = (f & 7) * 128;
    gemm_loop<4>(hs16, Wkt, HID, m0, n0, As, Bs, acc);
    bf16_store(acc, k16, 1024, m0, n0);
  } else {
    int f = b - 640, m0 = (f >> 4) * 128, n0 = (f & 15) * 128;
    gemm_loop<4>(Wvt, hs16, HID, m0, n0, As, Bs, acc);
    bf16_store(acc, v16t, T_SEQ, m0, n0);
  }
}

// Output projection: 64x128 tiles (512 blocks = 2/CU).
__global__ __launch_bounds__(256) void gemm_out(
    const ushort* __restrict__ ob16, const ushort* __restrict__ Wot,
    float* __restrict__ out) {
  __shared__ ushort As[64 * 32];
  __shared__ ushort Bs[128 * 32];
  f32x4 acc[2][4];
#pragma unroll
  for (int i = 0; i < 2; ++i)
#pragma unroll
    for (int j = 0; j < 4; ++j) acc[i][j] = (f32x4){0.f, 0.f, 0.f, 0.f};
  const int b = blockIdx.x;
  const int m0 = (b >> 4) * 64, n0 = (b & 15) * 128;
  gemm_loop<2>(ob16, Wot, HID, m0, n0, As, Bs, acc);
  const int lane = threadIdx.x & 63, w = threadIdx.x >> 6;
  const int quad = lane >> 4, l15 = lane & 15;
  const int wm = (w >> 1) * 32, wn = (w & 1) * 64;
#pragma unroll
  for (int mi = 0; mi < 2; ++mi)
#pragma unroll
    for (int ni = 0; ni < 4; ++ni)
#pragma unroll
      for (int r = 0; r < 4; ++r) {
        int row = m0 + wm + mi * 16 + quad * 4 + r;
        int col = n0 + wn + ni * 16 + l15;
        out[(size_t)row * HID + col] = acc[mi][ni][r];
      }
}

// ---------------- RMSNorm + RoPE for q AND k, in place --------------------
// grid (T_SEQ, NH+NKV), block 128. Buffers are [t][h][128].
__global__ __launch_bounds__(128) void norm_qk(
    ushort* __restrict__ q16, ushort* __restrict__ k16,
    const int* __restrict__ positions, const float* __restrict__ qw,
    const float* __restrict__ kw) {
  const int t = blockIdx.x, hh = blockIdx.y, d = threadIdx.x;
  ushort* x; const float* wgt;
  if (hh < NH) { x = q16 + ((size_t)t * NH + hh) * DH; wgt = qw; }
  else         { x = k16 + ((size_t)t * NKV + (hh - NH)) * DH; wgt = kw; }
  float v = bf2f(x[d]);
  float ss = v * v;
#pragma unroll
  for (int off = 32; off >= 1; off >>= 1) ss += __shfl_xor(ss, off, 64);
  __shared__ float red[2];
  if ((d & 63) == 0) red[d >> 6] = ss;
  __syncthreads();
  float mean = (red[0] + red[1]) * (1.0f / 128.0f);
  float xn = v * rsqrtf(mean + 1e-6f) * (1.0f + wgt[d]);
  __shared__ float sh[128];
  sh[d] = xn;
  __syncthreads();
  if (d < 64) {
    float pos = (float)positions[t];
    // angle in revolutions: pos * 10000^(-d/64) / (2*pi)
    float rev = pos * exp2f((float)d * -0.20762050593045233f) *
                0.15915494309189535f;
    float fr = rev - floorf(rev);
    float s = __builtin_amdgcn_sinf(fr);
    float c = __builtin_amdgcn_cosf(fr);
    float x1 = sh[d], x2 = sh[d + 64];
    x[d]      = f2bf(x1 * c - x2 * s);
    x[d + 64] = f2bf(x2 * c + x1 * s);
  }
}

// ---------------- MFMA flash attention, key-split x3, single-buffer -------
// grid (16, NH, 3): block (pb,h,s) does q-tiles {pb, 31-pb}, k-tiles
// kt ≡ s (mod 3). q16/k16 arrive pre-normed+roped. Static softmax bound B
// -> partials summable; combine_kernel merges the 3 splits.
__global__ __launch_bounds__(256) void attn_mfma(
    const ushort* __restrict__ q16, const ushort* __restrict__ k16,
    const ushort* __restrict__ v16t, const float* __restrict__ qnw,
    const float* __restrict__ knw, ushort* __restrict__ Op0,
    ushort* __restrict__ Op1, ushort* __restrict__ Op2,
    float* __restrict__ lpart) {
  const int pb = blockIdx.x, h = blockIdx.y, s = blockIdx.z, kvh = h >> 1;
  const int tid = threadIdx.x, lane = tid & 63, w = tid >> 6;
  const int quad = lane >> 4, l15 = lane & 15;

  __shared__ ushort Ks[64 * 128];     // 16 KB
  __shared__ ushort Vs[144 * 64];     // 18 KB; rows 128..143 constant
  __shared__ ushort Ps[4][16][72];    // 9.2 KB, per-wave

  // constant rows of Vs: row 128 = 1.0 (row-sum via MFMA), 129..143 = 0
  for (int i = tid; i < 16 * 64; i += 256) {
    int row = 128 + (i >> 6), col = i & 63;
    Vs[row * 64 + col] = (row == 128) ? (ushort)0x3F80 : (ushort)0;
  }

  // score bound B (log2 domain)
  __shared__ float s8[8];
  __shared__ float bshare;
  {
    float mq = 0.f, mk = 0.f;
    if (tid < 128) { mq = fabsf(1.f + qnw[tid]); mk = fabsf(1.f + knw[tid]); }
#pragma unroll
    for (int off = 32; off >= 1; off >>= 1) {
      mq = fmaxf(mq, __shfl_xor(mq, off, 64));
      mk = fmaxf(mk, __shfl_xor(mk, off, 64));
    }
    if (lane == 0) { s8[w * 2] = mq; s8[w * 2 + 1] = mk; }
    __syncthreads();
    if (tid == 0) {
      float MQ = fmaxf(s8[0], s8[2]), MK = fmaxf(s8[1], s8[3]);
      bshare = 16.3217f * MQ * MK * 1.02f + 0.1f;  // sqrt(128)*log2e + margin
    }
    __syncthreads();
  }
  const float B = bshare;
  const float CSC = 0.08838834764831845f * 1.44269504088896f;  // scale*log2e

#pragma unroll 1
  for (int sel = 0; sel < 2; ++sel) {
    const int qt = sel ? (31 - pb) : pb;
    const int q0 = qt * 64;
    const int ntl = (qt >= s) ? ((qt - s) / 3 + 1) : 0;  // tiles s, s+3, ...

    bf16x8 qf[4];
    const ushort* qbase = q16 + ((size_t)(q0 + w * 16 + l15) * NH + h) * DH;
#pragma unroll
    for (int ks = 0; ks < 4; ++ks)
      qf[ks] = *(const bf16x8*)(qbase + ks * 32 + quad * 8);

    f32x4 oacc[9];
#pragma unroll
    for (int i = 0; i < 9; ++i) oacc[i] = (f32x4){0.f, 0.f, 0.f, 0.f};

#pragma unroll 1
    for (int it = 0; it < ntl; ++it) {
      const int kt = s + 3 * it;
      const int kt0 = kt * 64;
      __syncthreads();  // all waves done reading Ks/Vs (prev iter / prev sel)
      // stage K tile: 64 rows x 16 chunks (swizzle ^(row&15))
#pragma unroll
      for (int p = 0; p < 4; ++p) {
        int row = p * 16 + (tid >> 4), ch = tid & 15;
        int gch = ch ^ (row & 15);
        gld16(k16 + ((size_t)(kt0 + row) * NKV + kvh) * DH + gch * 8,
              Ks + (p * 256 + w * 64) * 8);
      }
      // stage V^T tile: 128 rows x 8 chunks (swizzle ^(row&7))
#pragma unroll
      for (int p = 0; p < 4; ++p) {
        int row = p * 32 + (tid >> 3), ch = tid & 7;
        int gch = ch ^ (row & 7);
        gld16(v16t + (size_t)(kvh * DH + row) * T_SEQ + kt0 + gch * 8,
              Vs + (p * 256 + w * 64) * 8);
      }
      __syncthreads();  // vmcnt drained -> tiles ready

      // S = Q K^T
      f32x4 sacc[4];
#pragma unroll
      for (int ni = 0; ni < 4; ++ni) sacc[ni] = (f32x4){0.f, 0.f, 0.f, 0.f};
#pragma unroll
      for (int ks = 0; ks < 4; ++ks)
#pragma unroll
        for (int ni = 0; ni < 4; ++ni) {
          int row = ni * 16 + l15;
          int pch = (ks * 4 + quad) ^ (row & 15);
          bf16x8 kf = *(const bf16x8*)(Ks + row * 128 + pch * 8);
          sacc[ni] = __builtin_amdgcn_mfma_f32_16x16x32_bf16(
              qf[ks], kf, sacc[ni], 0, 0, 0);
        }

      // p = exp2(s*CSC - B); mask only on the diagonal tile
      const bool diag = (kt == qt);
#pragma unroll
      for (int ni = 0; ni < 4; ++ni) {
        int key = kt0 + ni * 16 + l15;
#pragma unroll
        for (int r = 0; r < 4; ++r) {
          float arg = fmaf(sacc[ni][r], CSC, -B);
          float pv;
          if (diag) {
            int q = q0 + w * 16 + quad * 4 + r;
            pv = (key <= q) ? exp2f(arg) : 0.f;
          } else {
            pv = exp2f(arg);
          }
          Ps[w][quad * 4 + r][ni * 16 + l15] = f2bf_rz(pv);
        }
      }

      // O += P V  (ni=8 tile: ones row -> row-sums accumulate in col 0)
#pragma unroll
      for (int ks2 = 0; ks2 < 2; ++ks2) {
        bf16x8 pf = *(const bf16x8*)(&Ps[w][l15][ks2 * 32 + quad * 8]);
#pragma unroll
        for (int ni = 0; ni < 9; ++ni) {
          int row = ni * 16 + l15;
          int pch = (ks2 * 4 + quad) ^ (row & 7);
          bf16x8 vf = *(const bf16x8*)(Vs + row * 64 + pch * 8);
          oacc[ni] = __builtin_amdgcn_mfma_f32_16x16x32_bf16(
              pf, vf, oacc[ni], 0, 0, 0);
        }
      }
    }

    // epilogue: write bf16 partial O ([h][q][d]) and fp32 partial l
    ushort* Op = (s == 0) ? Op0 : (s == 1) ? Op1 : Op2;
#pragma unroll
    for (int ni = 0; ni < 8; ++ni) {
      int d = ni * 16 + l15;
#pragma unroll
      for (int r = 0; r < 4; ++r) {
        int q = q0 + w * 16 + quad * 4 + r;
        Op[((size_t)h * T_SEQ + q) * DH + d] = f2bf(oacc[ni][r]);
      }
    }
    if (l15 == 0) {   // lane quad*16 holds l for its 4 rows in oacc[8]
#pragma unroll
      for (int r = 0; r < 4; ++r) {
        int q = q0 + w * 16 + quad * 4 + r;
        lpart[(size_t)s * (NH * T_SEQ) + h * T_SEQ + q] = oacc[8][r];
      }
    }
  }
}

// ---------------- combine: O=(ΣOp)/(Σl) * sigmoid(gate) -> ob16 ----------
__global__ __launch_bounds__(256) void combine_kernel(
    const ushort* __restrict__ Op0, const ushort* __restrict__ Op1,
    const ushort* __restrict__ Op2, const float* __restrict__ lpart,
    const ushort* __restrict__ gate16, ushort* __restrict__ ob16) {
  const int t = blockIdx.x, tid = threadIdx.x;
  const int h = tid >> 4, d0 = (tid & 15) * 8;
  const int NT = NH * T_SEQ;
  const float l = lpart[h * T_SEQ + t] + lpart[NT + h * T_SEQ + t] +
                  lpart[2 * NT + h * T_SEQ + t];
  const float inv = 1.0f / l;
  const size_t po = ((size_t)h * T_SEQ + t) * DH + d0;
  ushort4 a0 = *(const ushort4*)(Op0 + po);
  ushort4 a1 = *(const ushort4*)(Op0 + po + 4);
  ushort4 b0 = *(const ushort4*)(Op1 + po);
  ushort4 b1 = *(const ushort4*)(Op1 + po + 4);
  ushort4 c0 = *(const ushort4*)(Op2 + po);
  ushort4 c1 = *(const ushort4*)(Op2 + po + 4);
  const ushort* gp = gate16 + (size_t)t * (NH * DH) + h * DH + d0;
  ushort4 g0 = *(const ushort4*)(gp);
  ushort4 g1 = *(const ushort4*)(gp + 4);
  float oa[8] = {bf2f(a0.x), bf2f(a0.y), bf2f(a0.z), bf2f(a0.w),
                 bf2f(a1.x), bf2f(a1.y), bf2f(a1.z), bf2f(a1.w)};
  float ob[8] = {bf2f(b0.x), bf2f(b0.y), bf2f(b0.z), bf2f(b0.w),
                 bf2f(b1.x), bf2f(b1.y), bf2f(b1.z), bf2f(b1.w)};
  float oc[8] = {bf2f(c0.x), bf2f(c0.y), bf2f(c0.z), bf2f(c0.w),
                 bf2f(c1.x), bf2f(c1.y), bf2f(c1.z), bf2f(c1.w)};
  float gg[8] = {bf2f(g0.x), bf2f(g0.y), bf2f(g0.z), bf2f(g0.w),
                 bf2f(g1.x), bf2f(g1.y), bf2f(g1.z), bf2f(g1.w)};
  ushort r[8];
#pragma unroll
  for (int i = 0; i < 8; ++i) {
    float o = (oa[i] + ob[i] + oc[i]) * inv;
    o = o / (1.0f + exp2f(-gg[i] * 1.44269504088896f));
    r[i] = f2bf(o);
  }
  ushort* op = ob16 + (size_t)t * (NH * DH) + h * DH + d0;
  *(ushort4*)(op)     = (ushort4){r[0], r[1], r[2], r[3]};
  *(ushort4*)(op + 4) = (ushort4){r[4], r[5], r[6], r[7]};
}

extern "C" void kernel_launch(void* const* d_in, const int* in_sizes, int n_in,
                              void* d_out, int out_size, void* d_ws, size_t ws_size,
                              hipStream_t stream) {
  const int*   positions = (const int*)d_in[0];
  const float* hs  = (const float*)d_in[1];
  const float* Wq  = (const float*)d_in[2];
  const float* Wk  = (const float*)d_in[3];
  const float* Wv  = (const float*)d_in[4];
  const float* Wo  = (const float*)d_in[5];
  const float* qnw = (const float*)d_in[6];
  const float* knw = (const float*)d_in[7];
  float* out = (float*)d_out;

  // workspace (64 MB), region reuse (MB offsets):
  // [0,8)   hs16 (prep->qkv)   -> Op0  (attn->combine)
  // [8,24)  Wqt  (prep->qkv)   -> Op1 [8,16), Op2 [16,24)
  // [24,28) Wkt  (prep->qkv)   -> ob16 [24,32) (combine->gemm_out)
  // [28,32) Wvt  (prep->qkv)
  // [32,36) v16t (qkv->attn)
  // [36,40) k16  (qkv->norm_qk->attn, in-place norm)
  // [40,48) q16  (qkv->norm_qk->attn, in-place norm)
  // [48,56) gate16 (qkv->combine)
  // [56,64) Wot  (prep->gemm_out)
  // lpart lives in d_out (16 MB fp32, dead until gemm_out overwrites it).
  const size_t MB = 1 << 20;
  uint8_t* ws = (uint8_t*)d_ws;
  ushort* hs16  = (ushort*)(ws + 0);
  ushort* Op0   = (ushort*)(ws + 0);
  ushort* Wqt   = (ushort*)(ws + 8 * MB);
  ushort* Op1   = (ushort*)(ws + 8 * MB);
  ushort* Op2   = (ushort*)(ws + 16 * MB);
  ushort* Wkt   = (ushort*)(ws + 24 * MB);
  ushort* ob16  = (ushort*)(ws + 24 * MB);
  ushort* Wvt   = (ushort*)(ws + 28 * MB);
  ushort* v16t  = (ushort*)(ws + 32 * MB);
  ushort* k16   = (ushort*)(ws + 36 * MB);
  ushort* q16   = (ushort*)(ws + 40 * MB);
  ushort* gate16= (ushort*)(ws + 48 * MB);
  ushort* Wot   = (ushort*)(ws + 56 * MB);
  float*  lpart = (float*)d_out;   // scratch until gemm_out writes out

  prep_kernel<<<8192, 256, 0, stream>>>(hs, Wq, Wk, Wv, Wo,
                                        hs16, Wqt, Wkt, Wvt, Wot);
  gemm_qkv<<<768, 256, 0, stream>>>(hs16, Wqt, Wkt, Wvt,
                                    q16, gate16, k16, v16t);
  norm_qk<<<dim3(T_SEQ, NH + NKV), 128, 0, stream>>>(q16, k16, positions,
                                                     qnw, knw);
  attn_mfma<<<dim3(16, NH, 3), 256, 0, stream>>>(q16, k16, v16t, qnw, knw,
                                                 Op0, Op1, Op2, lpart);
  combine_kernel<<<T_SEQ, 256, 0, stream>>>(Op0, Op1, Op2, lpart, gate16, ob16);
  gemm_out<<<512, 256, 0, stream>>>(ob16, Wot, out);
}